// Round 10
// baseline (296.145 us; speedup 1.0000x reference)
//
#include <hip/hip_runtime.h>

// stackCLSTM: T=32, B=128, I=64, H=128, E=4, N_TRAP=100
// ws layout (float-word offsets):
//   W_all  [64][3072] fp32        @ 0         (196608)
//   bias   [3072] fp32            @ 196608    (3072)
//   WhhH   [e][kq][i4][lane][q]   @ 199680    (131072)  fp16-pair packed Whh h-part (uint4 rows)
//   WgH    [e][kq][16][5][128] u32@ 330752    (163840)  fp16-pair packed gate h-part
//   XG     [4096][3072] fp32      @ 494592    (12582912)
//   hbuf   [2][64][4][2][64] u32  @ 21466112  (65536)   fp16-pair packed h state
//   flags  [64][32][4] int        @ 21531648  (8192)    per-producer per-step ready flags
#define OFF_WALL   0
#define OFF_BIAS   196608
#define OFF_WHHH   199680
#define OFF_WGH    330752
#define OFF_XG     494592
#define OFF_HBUF   21466112
#define OFF_FLAGS  21531648

typedef _Float16 half2_t __attribute__((ext_vector_type(2)));

__device__ __forceinline__ float fast_sig(float x) {
    return __fdividef(1.f, 1.f + __expf(-x));
}
__device__ __forceinline__ float sigt(float x) {      // 1/(exp(x)+1)
    return __fdividef(1.f, __expf(x) + 1.f);
}
__device__ __forceinline__ unsigned pack2h(float a, float b) {
    _Float16 ha = (_Float16)a, hb = (_Float16)b;
    unsigned short ua = __builtin_bit_cast(unsigned short, ha);
    unsigned short ub = __builtin_bit_cast(unsigned short, hb);
    return ((unsigned)ub << 16) | ua;
}
__device__ __forceinline__ float dot2(unsigned w, unsigned h, float acc) {
    return __builtin_amdgcn_fdot2(__builtin_bit_cast(half2_t, w),
                                  __builtin_bit_cast(half2_t, h), acc, false);
}

// ---------------- K0: pack weights + zero flags ----------------
__global__ __launch_bounds__(256) void k0_pack(
    const float* __restrict__ Wh_w, const float* __restrict__ Wh_b,
    const float* __restrict__ Wi_w, const float* __restrict__ Wi_b,
    const float* __restrict__ Wf_w, const float* __restrict__ Wf_b,
    const float* __restrict__ Wd_w, const float* __restrict__ Wd_b,
    const float* __restrict__ Wg_w, const float* __restrict__ Wg_b,
    const float* __restrict__ Wo_w, const float* __restrict__ Wo_b,
    float* __restrict__ ws)
{
    const float* gw[5] = {Wi_w, Wf_w, Wd_w, Wg_w, Wo_w};
    const float* gb[5] = {Wi_b, Wf_b, Wd_b, Wg_b, Wo_b};
    int idx = blockIdx.x * 256 + threadIdx.x;
    if (idx < 196608) {            // W_all [r<64][col<3072]
        int r = idx / 3072, col = idx - r * 3072;
        float v;
        if (col < 512) {
            v = Wh_w[r * 512 + col] + Wh_w[(192 + r) * 512 + col]
              + Wh_w[(384 + r) * 512 + col] + Wh_w[(576 + r) * 512 + col];
        } else {
            int q = col - 512;
            int e = q / 640;
            int rem = q - e * 640;
            int g = rem >> 7, h = rem & 127;
            v = gw[g][(e * 192 + r) * 128 + h];
        }
        ws[OFF_WALL + idx] = v;
    } else if (idx < 327680) {     // WhhH [e][kq][i4][lane][q]  (uint4-per-lane rows)
        int i = idx - 196608;
        int q    = i & 3;
        int lane = (i >> 2) & 127;
        int i4   = (i >> 9) & 15;
        int kq   = (i >> 13) & 3;
        int e    = i >> 15;
        int kp = i4 * 4 + q;
        int k0 = kq * 128 + 2 * kp;
        int r0 = (k0 >> 7) * 192 + 64 + (k0 & 127);
        float w0 = Wh_w[r0 * 512 + e * 128 + lane];
        float w1 = Wh_w[(r0 + 1) * 512 + e * 128 + lane];
        reinterpret_cast<unsigned*>(ws + OFF_WHHH)[i] = pack2h(w0, w1);
    } else if (idx < 491520) {     // WgH [e][kq][16 ii][5 g][128 lane]
        int i = idx - 327680;
        int lane = i & 127;
        int gg = (i >> 7) % 5;
        int rest = (i >> 7) / 5;
        int ii = rest & 15;
        int kq = (rest >> 4) & 3;
        int e  = rest >> 6;
        int k0 = kq * 32 + 2 * ii, k1 = k0 + 1;
        float w0 = gw[gg][(e * 192 + 64 + k0) * 128 + lane];
        float w1 = gw[gg][(e * 192 + 64 + k1) * 128 + lane];
        reinterpret_cast<unsigned*>(ws + OFF_WGH)[i] = pack2h(w0, w1);
    }
    if (idx < 3072) {              // bias
        float v;
        if (idx < 512) v = Wh_b[idx];
        else {
            int q = idx - 512;
            int e = q / 640;
            int rem = q - e * 640;
            int g = rem >> 7, h = rem & 127;
            v = gb[g][e * 128 + h];
        }
        ws[OFF_BIAS + idx] = v;
    }
    if (idx < 8192) {              // zero per-producer flags every launch (graph-safe)
        reinterpret_cast<int*>(ws + OFF_FLAGS)[idx] = 0;
    }
}

// ---------------- K1: XG[4096][3072] = X[4096][64] @ W_all + bias ----------------
__global__ __launch_bounds__(256) void k1_xproj(
    const float* __restrict__ x, const float* wsr, float* XG)
{
    __shared__ __align__(16) float XT[64 * 68];
    const float* W_all = wsr + OFF_WALL;
    const float* bias  = wsr + OFF_BIAS;
    int bid = blockIdx.x;
    int ct = bid % 48, rt = bid / 48;
    int r0 = rt * 64, c0 = ct * 64;
    for (int p = threadIdx.x; p < 4096; p += 256) {
        int i = p >> 6, k = p & 63;
        XT[k * 68 + i] = x[(r0 + i) * 64 + k];
    }
    __syncthreads();
    int col = c0 + (threadIdx.x & 63);
    int iq = threadIdx.x >> 6;
    float acc[16];
    #pragma unroll
    for (int r = 0; r < 16; r++) acc[r] = 0.f;
    const float* wp = W_all + col;
    #pragma unroll 4
    for (int k = 0; k < 64; k++) {
        float w = wp[k * 3072];
        const float4* xt4 = reinterpret_cast<const float4*>(&XT[k * 68 + iq * 16]);
        #pragma unroll
        for (int r4 = 0; r4 < 4; r4++) {
            float4 xv = xt4[r4];
            acc[r4 * 4 + 0] = fmaf(xv.x, w, acc[r4 * 4 + 0]);
            acc[r4 * 4 + 1] = fmaf(xv.y, w, acc[r4 * 4 + 1]);
            acc[r4 * 4 + 2] = fmaf(xv.z, w, acc[r4 * 4 + 2]);
            acc[r4 * 4 + 3] = fmaf(xv.w, w, acc[r4 * 4 + 3]);
        }
    }
    float bv = bias[col];
    #pragma unroll
    for (int r = 0; r < 16; r++) {
        int row = r0 + iq * 16 + r;
        XG[row * 3072 + col] = acc[r] + bv;
    }
}

// ---------------- K2: recurrence + fused trapezoid ----------------
// 256 blocks x 512 threads, 1 block/CU (LDS-capped). Group of 4 (one per e) = 1 batch pair.
// Whh in LDS; gate weights streamed/reg by compiler. Per-producer flags (no RMW).
// Trapezoid integral computed per step from register state, hidden in the sync slack.
__global__ __launch_bounds__(512, 1) void k2_recur(
    const uint4* __restrict__ WhhH4,
    const unsigned* __restrict__ WgH,
    const float* __restrict__ XG,
    const float* __restrict__ dt_time,
    const float* __restrict__ alpha,
    unsigned* __restrict__ hbuf,
    int* __restrict__ flags,
    float* __restrict__ lam_out,
    float* __restrict__ integ_out)
{
    __shared__ __align__(16) uint4 waL[8192];       // 128 KB
    __shared__ __align__(16) unsigned hL[256][2];
    __shared__ __align__(16) float hsF[2][128];
    __shared__ float pA[4][2][128];
    __shared__ float pB[4][2][5][128];
    __shared__ float red[4];
    __shared__ float red2[4];
    const int tid = threadIdx.x;
    const int bid = blockIdx.x;
    const int e   = (bid >> 3) & 3;
    const int grp = (bid & 7) | ((bid >> 5) << 3);
    const int b0  = grp * 2;
    const int kq  = tid >> 7;
    const int lane = tid & 127;
    const int s = (tid >> 7) & 1, l = lane;

    // stage Whh e-slice into LDS (once)
    {
        const uint4* src = WhhH4 + (size_t)e * 8192;
        #pragma unroll
        for (int n = 0; n < 16; ++n) waL[tid + 512 * n] = src[tid + 512 * n];
    }
    // gate weights (compiler decides reg/L2; streaming proved cheap)
    unsigned wg[5][16];
    #pragma unroll
    for (int i = 0; i < 16; i++) {
        #pragma unroll
        for (int g = 0; g < 5; g++)
            wg[g][i] = WgH[(((e * 4 + kq) * 16 + i) * 5 + g) * 128 + lane];
    }
    const float av = alpha[e * 128 + lane];
    int* gflag = flags + grp * 128;        // [t][4]
    float cst = 0.f;
    __syncthreads();   // waL ready

    for (int t = 0; t < 32; ++t) {
        const int row0 = t * 128 + b0;
        // (1) XG prefetch
        float xg0 = 0.f, xgg0 = 0.f, xgg1 = 0.f, xgg2 = 0.f, xgg3 = 0.f, xgg4 = 0.f;
        if (tid < 256) {
            const float* base = XG + (size_t)(row0 + s) * 3072;
            xg0 = base[e * 128 + l];
            const float* gp = base + 512 + e * 640 + l;
            xgg0 = gp[0]; xgg1 = gp[128]; xgg2 = gp[256]; xgg3 = gp[384]; xgg4 = gp[512];
        }
        if (t > 0) {
            // (2) wait for all 4 producer flags of step t-1 (plain relaxed IC loads)
            if (tid == 0) {
                const int fb = (t - 1) * 4;
                for (;;) {
                    int a = __hip_atomic_load(&gflag[fb + 0], __ATOMIC_RELAXED, __HIP_MEMORY_SCOPE_AGENT);
                    int b = __hip_atomic_load(&gflag[fb + 1], __ATOMIC_RELAXED, __HIP_MEMORY_SCOPE_AGENT);
                    int c = __hip_atomic_load(&gflag[fb + 2], __ATOMIC_RELAXED, __HIP_MEMORY_SCOPE_AGENT);
                    int d = __hip_atomic_load(&gflag[fb + 3], __ATOMIC_RELAXED, __HIP_MEMORY_SCOPE_AGENT);
                    if (a & b & c & d) break;
                    __builtin_amdgcn_s_sleep(1);
                }
            }
            __syncthreads();
            asm volatile("" ::: "memory");
            // (3) stage h -> LDS (IC-direct relaxed loads)
            {
                const unsigned* src = hbuf + (size_t)((t & 1) * 64 + grp) * 512;
                unsigned v = __hip_atomic_load(&src[tid], __ATOMIC_RELAXED,
                                               __HIP_MEMORY_SCOPE_AGENT);
                int eh = tid >> 7, sh = (tid >> 6) & 1, p = tid & 63;
                hL[eh * 64 + p][sh] = v;
            }
            __syncthreads();
            // (4) phase A: hs partial dots (wa from LDS)
            float a0 = 0.f, a1 = 0.f;
            {
                const uint2* hL2 = reinterpret_cast<const uint2*>(hL);
                #pragma unroll
                for (int i4 = 0; i4 < 16; ++i4) {
                    uint4 w = waL[(kq * 16 + i4) * 128 + lane];
                    uint2 h0 = hL2[kq * 64 + i4 * 4 + 0];
                    uint2 h1 = hL2[kq * 64 + i4 * 4 + 1];
                    uint2 h2 = hL2[kq * 64 + i4 * 4 + 2];
                    uint2 h3 = hL2[kq * 64 + i4 * 4 + 3];
                    a0 = dot2(w.x, h0.x, a0); a1 = dot2(w.x, h0.y, a1);
                    a0 = dot2(w.y, h1.x, a0); a1 = dot2(w.y, h1.y, a1);
                    a0 = dot2(w.z, h2.x, a0); a1 = dot2(w.z, h2.y, a1);
                    a0 = dot2(w.w, h3.x, a0); a1 = dot2(w.w, h3.y, a1);
                }
            }
            pA[kq][0][lane] = a0;
            pA[kq][1][lane] = a1;
            __syncthreads();
            if (tid < 256) {
                float hs = pA[0][s][l] + pA[1][s][l] + pA[2][s][l] + pA[3][s][l] + xg0;
                hsF[s][l] = hs;
            }
        } else {
            if (tid < 256) hsF[s][l] = xg0;
        }
        __syncthreads();
        // (5) phase B: gate partial dots
        float b0a = 0.f, b1a = 0.f, b2a = 0.f, b3a = 0.f, b4a = 0.f;
        float b0b = 0.f, b1b = 0.f, b2b = 0.f, b3b = 0.f, b4b = 0.f;
        #pragma unroll
        for (int i = 0; i < 16; i++) {
            float2 f0 = *reinterpret_cast<const float2*>(&hsF[0][kq * 32 + 2 * i]);
            float2 f1 = *reinterpret_cast<const float2*>(&hsF[1][kq * 32 + 2 * i]);
            unsigned h0 = pack2h(f0.x, f0.y);
            unsigned h1 = pack2h(f1.x, f1.y);
            b0a = dot2(wg[0][i], h0, b0a); b0b = dot2(wg[0][i], h1, b0b);
            b1a = dot2(wg[1][i], h0, b1a); b1b = dot2(wg[1][i], h1, b1b);
            b2a = dot2(wg[2][i], h0, b2a); b2b = dot2(wg[2][i], h1, b2b);
            b3a = dot2(wg[3][i], h0, b3a); b3b = dot2(wg[3][i], h1, b3b);
            b4a = dot2(wg[4][i], h0, b4a); b4b = dot2(wg[4][i], h1, b4b);
        }
        pB[kq][0][0][lane] = b0a; pB[kq][0][1][lane] = b1a; pB[kq][0][2][lane] = b2a;
        pB[kq][0][3][lane] = b3a; pB[kq][0][4][lane] = b4a;
        pB[kq][1][0][lane] = b0b; pB[kq][1][1][lane] = b1b; pB[kq][1][2][lane] = b2b;
        pB[kq][1][3][lane] = b3b; pB[kq][1][4][lane] = b4b;
        __syncthreads();
        // (6) cell update (tid<256); keep state in regs for the fused trapezoid
        float gc = 0.f, df = 0.f, dl = 0.f, og = 0.f, dtv = 0.f;
        if (tid < 256) {
            float ai = pB[0][s][0][l] + pB[1][s][0][l] + pB[2][s][0][l] + pB[3][s][0][l] + xgg0;
            float af = pB[0][s][1][l] + pB[1][s][1][l] + pB[2][s][1][l] + pB[3][s][1][l] + xgg1;
            float ad = pB[0][s][2][l] + pB[1][s][2][l] + pB[2][s][2][l] + pB[3][s][2][l] + xgg2;
            float ag = pB[0][s][3][l] + pB[1][s][3][l] + pB[2][s][3][l] + pB[3][s][3][l] + xgg3;
            float ao = pB[0][s][4][l] + pB[1][s][4][l] + pB[2][s][4][l] + pB[3][s][4][l] + xgg4;
            float ig = fast_sig(ai);
            float fg = fast_sig(af);
            dl = __expf(ad);
            float gt = tanhf(ag);
            og = fast_sig(ao);
            gc = fmaf(fg, cst, ig * gt);
            df = cst - gc;
            dtv = dt_time[row0 + s];
            cst = fmaf(df, __expf(-dl * dtv), gc);
            float hn = og * tanhf(cst);
            // h_new -> hbuf parity (t+1)&1 (IC-direct)
            float hi = __shfl_down(hn, 1, 64);
            if ((l & 1) == 0) {
                unsigned* dst = hbuf
                    + (size_t)(((t + 1) & 1) * 64 + grp) * 512
                    + (e * 2 + s) * 64 + (l >> 1);
                __hip_atomic_store(dst, pack2h(hn, hi), __ATOMIC_RELAXED,
                                   __HIP_MEMORY_SCOPE_AGENT);
            }
            float lm = av * hn;
            #pragma unroll
            for (int off = 32; off > 0; off >>= 1) lm += __shfl_down(lm, off, 64);
            if ((tid & 63) == 0) red[tid >> 6] = lm;
        }
        __syncthreads();   // drains h stores (vmcnt 0) before flag release
        if (tid == 0) {
            lam_out[(row0 + 0) * 4 + e] = red[0] + red[1];
            lam_out[(row0 + 1) * 4 + e] = red[2] + red[3];
            __hip_atomic_store(&gflag[t * 4 + e], 1, __ATOMIC_RELAXED,
                               __HIP_MEMORY_SCOPE_AGENT);
        }
        // (7) fused trapezoid: Σ_{k=0..100} w_k tanh(gc + df·exp(-δ·dt·k/100)),
        //     w_0=w_100=0.5. tanh(x)=1-2/(e^{2x}+1); 4 geometric chains for ILP.
        if (tid < 256) {
            float g2 = 2.f * gc, d2 = 2.f * df;
            float q  = dl * dtv;
            float r1 = __expf(-q * 0.01f);
            float r2 = r1 * r1;
            float r4 = r2 * r2;
            float E100 = __expf(-q);
            float sE = 0.5f * sigt(g2 + d2) - 0.5f * sigt(fmaf(d2, E100, g2));
            float E1 = r1, E2 = r2, E3 = r2 * r1, E4 = r4;
            float s1 = 0.f, s2 = 0.f, s3 = 0.f, s4 = 0.f;
            #pragma unroll 1
            for (int k = 0; k < 25; ++k) {      // covers k=1..100
                s1 += sigt(fmaf(d2, E1, g2)); E1 *= r4;
                s2 += sigt(fmaf(d2, E2, g2)); E2 *= r4;
                s3 += sigt(fmaf(d2, E3, g2)); E3 *= r4;
                s4 += sigt(fmaf(d2, E4, g2)); E4 *= r4;
            }
            sE += (s1 + s2) + (s3 + s4);
            float iv = av * og * (100.f - 2.f * sE) * (dtv * 0.01f);
            #pragma unroll
            for (int off = 32; off > 0; off >>= 1) iv += __shfl_down(iv, off, 64);
            if ((tid & 63) == 0) red2[tid >> 6] = iv;
        }
        __syncthreads();
        if (tid == 0) {
            integ_out[(row0 + 0) * 4 + e] = red2[0] + red2[1];
            integ_out[(row0 + 1) * 4 + e] = red2[2] + red2[3];
        }
    }
}

extern "C" void kernel_launch(void* const* d_in, const int* in_sizes, int n_in,
                              void* d_out, int out_size, void* d_ws, size_t ws_size,
                              hipStream_t stream)
{
    const float* x_time  = (const float*)d_in[0];
    const float* dt_time = (const float*)d_in[1];
    const float* Wh_w = (const float*)d_in[2];
    const float* Wh_b = (const float*)d_in[3];
    const float* Wi_w = (const float*)d_in[4];
    const float* Wi_b = (const float*)d_in[5];
    const float* Wf_w = (const float*)d_in[6];
    const float* Wf_b = (const float*)d_in[7];
    const float* Wd_w = (const float*)d_in[8];
    const float* Wd_b = (const float*)d_in[9];
    const float* Wg_w = (const float*)d_in[10];
    const float* Wg_b = (const float*)d_in[11];
    const float* Wo_w = (const float*)d_in[12];
    const float* Wo_b = (const float*)d_in[13];
    const float* alpha = (const float*)d_in[14];

    float* ws = (float*)d_ws;
    float* XG   = ws + OFF_XG;
    unsigned* hbuf = (unsigned*)(ws + OFF_HBUF);
    int*   flags = (int*)(ws + OFF_FLAGS);
    float* lam_out   = (float*)d_out;
    float* integ_out = lam_out + 32 * 128 * 4;

    k0_pack<<<3072, 256, 0, stream>>>(Wh_w, Wh_b, Wi_w, Wi_b, Wf_w, Wf_b,
                                      Wd_w, Wd_b, Wg_w, Wg_b, Wo_w, Wo_b, ws);
    k1_xproj<<<3072, 256, 0, stream>>>(x_time, ws, XG);
    k2_recur<<<256, 512, 0, stream>>>(
        (const uint4*)(ws + OFF_WHHH), (const unsigned*)(ws + OFF_WGH),
        XG, dt_time, alpha, hbuf, flags, lam_out, integ_out);
}

// Round 11
// 274.305 us; speedup vs baseline: 1.0796x; 1.0796x over previous
//
#include <hip/hip_runtime.h>

// stackCLSTM: T=32, B=128, I=64, H=128, E=4, N_TRAP=100
// ws layout (float-word offsets):
//   W_all  [64][3072] fp32        @ 0         (196608)
//   bias   [3072] fp32            @ 196608    (3072)
//   WhhH   [e][kq][i4][lane][q]   @ 199680    (131072)  fp16-pair packed Whh h-part (uint4 rows)
//   WgH    [e][kq][16][5][128] u32@ 330752    (163840)  fp16-pair packed gate h-part
//   XG     [4096][3072] fp32      @ 494592    (12582912)
//   Gst    [4][4096*512] fp32     @ 13077504  (8388608)
//   hbuf   [2][64][4 copy][512] u32 @ 21466112 (262144) data-as-flag h exchange (sentinel 0xFFFFFFFF)
#define OFF_WALL   0
#define OFF_BIAS   196608
#define OFF_WHHH   199680
#define OFF_WGH    330752
#define OFF_XG     494592
#define OFF_GST    13077504
#define OFF_HBUF   21466112
#define GST_PLANE  2097152
#define H_SENT     0xFFFFFFFFu

typedef _Float16 half2_t __attribute__((ext_vector_type(2)));

__device__ __forceinline__ float fast_sig(float x) {
    return __fdividef(1.f, 1.f + __expf(-x));
}
__device__ __forceinline__ float sigt(float x) {      // 1/(exp(x)+1)
    return __fdividef(1.f, __expf(x) + 1.f);
}
__device__ __forceinline__ unsigned pack2h(float a, float b) {
    _Float16 ha = (_Float16)a, hb = (_Float16)b;
    unsigned short ua = __builtin_bit_cast(unsigned short, ha);
    unsigned short ub = __builtin_bit_cast(unsigned short, hb);
    return ((unsigned)ub << 16) | ua;
}
__device__ __forceinline__ float dot2(unsigned w, unsigned h, float acc) {
    return __builtin_amdgcn_fdot2(__builtin_bit_cast(half2_t, w),
                                  __builtin_bit_cast(half2_t, h), acc, false);
}

// ---------------- K0: pack weights + sentinel-fill hbuf ----------------
__global__ __launch_bounds__(256) void k0_pack(
    const float* __restrict__ Wh_w, const float* __restrict__ Wh_b,
    const float* __restrict__ Wi_w, const float* __restrict__ Wi_b,
    const float* __restrict__ Wf_w, const float* __restrict__ Wf_b,
    const float* __restrict__ Wd_w, const float* __restrict__ Wd_b,
    const float* __restrict__ Wg_w, const float* __restrict__ Wg_b,
    const float* __restrict__ Wo_w, const float* __restrict__ Wo_b,
    float* __restrict__ ws)
{
    const float* gw[5] = {Wi_w, Wf_w, Wd_w, Wg_w, Wo_w};
    const float* gb[5] = {Wi_b, Wf_b, Wd_b, Wg_b, Wo_b};
    int idx = blockIdx.x * 256 + threadIdx.x;
    if (idx < 196608) {            // W_all [r<64][col<3072]
        int r = idx / 3072, col = idx - r * 3072;
        float v;
        if (col < 512) {
            v = Wh_w[r * 512 + col] + Wh_w[(192 + r) * 512 + col]
              + Wh_w[(384 + r) * 512 + col] + Wh_w[(576 + r) * 512 + col];
        } else {
            int q = col - 512;
            int e = q / 640;
            int rem = q - e * 640;
            int g = rem >> 7, h = rem & 127;
            v = gw[g][(e * 192 + r) * 128 + h];
        }
        ws[OFF_WALL + idx] = v;
    } else if (idx < 327680) {     // WhhH [e][kq][i4][lane][q]  (uint4-per-lane rows)
        int i = idx - 196608;
        int q    = i & 3;
        int lane = (i >> 2) & 127;
        int i4   = (i >> 9) & 15;
        int kq   = (i >> 13) & 3;
        int e    = i >> 15;
        int kp = i4 * 4 + q;
        int k0 = kq * 128 + 2 * kp;
        int r0 = (k0 >> 7) * 192 + 64 + (k0 & 127);
        float w0 = Wh_w[r0 * 512 + e * 128 + lane];
        float w1 = Wh_w[(r0 + 1) * 512 + e * 128 + lane];
        reinterpret_cast<unsigned*>(ws + OFF_WHHH)[i] = pack2h(w0, w1);
    } else if (idx < 491520) {     // WgH [e][kq][16 ii][5 g][128 lane]
        int i = idx - 327680;
        int lane = i & 127;
        int gg = (i >> 7) % 5;
        int rest = (i >> 7) / 5;
        int ii = rest & 15;
        int kq = (rest >> 4) & 3;
        int e  = rest >> 6;
        int k0 = kq * 32 + 2 * ii, k1 = k0 + 1;
        float w0 = gw[gg][(e * 192 + 64 + k0) * 128 + lane];
        float w1 = gw[gg][(e * 192 + 64 + k1) * 128 + lane];
        reinterpret_cast<unsigned*>(ws + OFF_WGH)[i] = pack2h(w0, w1);
    }
    if (idx < 3072) {              // bias
        float v;
        if (idx < 512) v = Wh_b[idx];
        else {
            int q = idx - 512;
            int e = q / 640;
            int rem = q - e * 640;
            int g = rem >> 7, h = rem & 127;
            v = gb[g][e * 128 + h];
        }
        ws[OFF_BIAS + idx] = v;
    }
    if (idx < 262144) {            // sentinel-fill hbuf every launch (graph-replay safe)
        reinterpret_cast<unsigned*>(ws + OFF_HBUF)[idx] = H_SENT;
    }
}

// ---------------- K1: XG[4096][3072] = X[4096][64] @ W_all + bias ----------------
__global__ __launch_bounds__(256) void k1_xproj(
    const float* __restrict__ x, const float* wsr, float* XG)
{
    __shared__ __align__(16) float XT[64 * 68];
    const float* W_all = wsr + OFF_WALL;
    const float* bias  = wsr + OFF_BIAS;
    int bid = blockIdx.x;
    int ct = bid % 48, rt = bid / 48;
    int r0 = rt * 64, c0 = ct * 64;
    for (int p = threadIdx.x; p < 4096; p += 256) {
        int i = p >> 6, k = p & 63;
        XT[k * 68 + i] = x[(r0 + i) * 64 + k];
    }
    __syncthreads();
    int col = c0 + (threadIdx.x & 63);
    int iq = threadIdx.x >> 6;
    float acc[16];
    #pragma unroll
    for (int r = 0; r < 16; r++) acc[r] = 0.f;
    const float* wp = W_all + col;
    #pragma unroll 4
    for (int k = 0; k < 64; k++) {
        float w = wp[k * 3072];
        const float4* xt4 = reinterpret_cast<const float4*>(&XT[k * 68 + iq * 16]);
        #pragma unroll
        for (int r4 = 0; r4 < 4; r4++) {
            float4 xv = xt4[r4];
            acc[r4 * 4 + 0] = fmaf(xv.x, w, acc[r4 * 4 + 0]);
            acc[r4 * 4 + 1] = fmaf(xv.y, w, acc[r4 * 4 + 1]);
            acc[r4 * 4 + 2] = fmaf(xv.z, w, acc[r4 * 4 + 2]);
            acc[r4 * 4 + 3] = fmaf(xv.w, w, acc[r4 * 4 + 3]);
        }
    }
    float bv = bias[col];
    #pragma unroll
    for (int r = 0; r < 16; r++) {
        int row = r0 + iq * 16 + r;
        XG[row * 3072 + col] = acc[r] + bv;
    }
}

// ---------------- K2: recurrence; data-as-flag sync (1 IC round trip/step) ----------------
// 256 blocks x 512 threads, 1 block/CU (LDS-capped). Group of 4 (one per e) = 1 batch pair.
// Whh in LDS, gates reg/L2. h exchange: producers write fp16-pair words to 4 private
// consumer copies; consumers poll their own word for != SENTINEL, then re-arm it.
// Own e-slice is taken from LDS hOut (persists across the step boundary) - no self-poll.
__global__ __launch_bounds__(512, 1) void k2_recur(
    const uint4* __restrict__ WhhH4,
    const unsigned* __restrict__ WgH,
    const float* __restrict__ XG,
    const float* __restrict__ dt_time,
    const float* __restrict__ alpha,
    float* __restrict__ Gst,
    unsigned* __restrict__ hbuf,
    float* __restrict__ lam_out)
{
    __shared__ __align__(16) uint4 waL[8192];       // 128 KB
    __shared__ __align__(16) unsigned hL[256][2];
    __shared__ __align__(16) float hsF[2][128];
    __shared__ __align__(16) unsigned hOut[128];    // this block's packed h (persists)
    __shared__ float pA[4][2][128];
    __shared__ float pB[4][2][5][128];
    __shared__ float red[4];
    const int tid = threadIdx.x;
    const int bid = blockIdx.x;
    const int e   = (bid >> 3) & 3;
    const int grp = (bid & 7) | ((bid >> 5) << 3);
    const int b0  = grp * 2;
    const int kq  = tid >> 7;
    const int lane = tid & 127;
    const int s = (tid >> 7) & 1, l = lane;

    // stage Whh e-slice into LDS (once)
    {
        const uint4* src = WhhH4 + (size_t)e * 8192;
        #pragma unroll
        for (int n = 0; n < 16; ++n) waL[tid + 512 * n] = src[tid + 512 * n];
    }
    unsigned wg[5][16];
    #pragma unroll
    for (int i = 0; i < 16; i++) {
        #pragma unroll
        for (int g = 0; g < 5; g++)
            wg[g][i] = WgH[(((e * 4 + kq) * 16 + i) * 5 + g) * 128 + lane];
    }
    const float av = alpha[e * 128 + lane];
    float cst = 0.f;
    __syncthreads();   // waL ready

    for (int t = 0; t < 32; ++t) {
        const int row0 = t * 128 + b0;
        // (1) XG prefetch
        float xg0 = 0.f, xgg0 = 0.f, xgg1 = 0.f, xgg2 = 0.f, xgg3 = 0.f, xgg4 = 0.f;
        if (tid < 256) {
            const float* base = XG + (size_t)(row0 + s) * 3072;
            xg0 = base[e * 128 + l];
            const float* gp = base + 512 + e * 640 + l;
            xgg0 = gp[0]; xgg1 = gp[128]; xgg2 = gp[256]; xgg3 = gp[384]; xgg4 = gp[512];
        }
        if (t > 0) {
            // (2+3) single-round-trip h acquire: poll own word of our private copy
            {
                const int eh = tid >> 7, sh = (tid >> 6) & 1, p = tid & 63;
                unsigned v;
                if (eh == e) {
                    v = hOut[tid & 127];            // own slice from LDS (prev step)
                } else {
                    unsigned* ap = hbuf + ((size_t)((t & 1) * 64 + grp) * 4 + e) * 512 + tid;
                    v = __hip_atomic_load(ap, __ATOMIC_RELAXED, __HIP_MEMORY_SCOPE_AGENT);
                    while (v == H_SENT) {
                        __builtin_amdgcn_s_sleep(1);
                        v = __hip_atomic_load(ap, __ATOMIC_RELAXED, __HIP_MEMORY_SCOPE_AGENT);
                    }
                    __hip_atomic_store(ap, H_SENT, __ATOMIC_RELAXED,
                                       __HIP_MEMORY_SCOPE_AGENT);   // re-arm
                }
                hL[eh * 64 + p][sh] = v;
            }
            __syncthreads();
            // (4) phase A: hs partial dots (wa from LDS)
            float a0 = 0.f, a1 = 0.f;
            {
                const uint2* hL2 = reinterpret_cast<const uint2*>(hL);
                #pragma unroll
                for (int i4 = 0; i4 < 16; ++i4) {
                    uint4 w = waL[(kq * 16 + i4) * 128 + lane];
                    uint2 h0 = hL2[kq * 64 + i4 * 4 + 0];
                    uint2 h1 = hL2[kq * 64 + i4 * 4 + 1];
                    uint2 h2 = hL2[kq * 64 + i4 * 4 + 2];
                    uint2 h3 = hL2[kq * 64 + i4 * 4 + 3];
                    a0 = dot2(w.x, h0.x, a0); a1 = dot2(w.x, h0.y, a1);
                    a0 = dot2(w.y, h1.x, a0); a1 = dot2(w.y, h1.y, a1);
                    a0 = dot2(w.z, h2.x, a0); a1 = dot2(w.z, h2.y, a1);
                    a0 = dot2(w.w, h3.x, a0); a1 = dot2(w.w, h3.y, a1);
                }
            }
            pA[kq][0][lane] = a0;
            pA[kq][1][lane] = a1;
            __syncthreads();
            if (tid < 256) {
                float hs = pA[0][s][l] + pA[1][s][l] + pA[2][s][l] + pA[3][s][l] + xg0;
                hsF[s][l] = hs;
            }
        } else {
            if (tid < 256) hsF[s][l] = xg0;
        }
        __syncthreads();
        // (5) phase B: gate partial dots
        float b0a = 0.f, b1a = 0.f, b2a = 0.f, b3a = 0.f, b4a = 0.f;
        float b0b = 0.f, b1b = 0.f, b2b = 0.f, b3b = 0.f, b4b = 0.f;
        #pragma unroll
        for (int i = 0; i < 16; i++) {
            float2 f0 = *reinterpret_cast<const float2*>(&hsF[0][kq * 32 + 2 * i]);
            float2 f1 = *reinterpret_cast<const float2*>(&hsF[1][kq * 32 + 2 * i]);
            unsigned h0 = pack2h(f0.x, f0.y);
            unsigned h1 = pack2h(f1.x, f1.y);
            b0a = dot2(wg[0][i], h0, b0a); b0b = dot2(wg[0][i], h1, b0b);
            b1a = dot2(wg[1][i], h0, b1a); b1b = dot2(wg[1][i], h1, b1b);
            b2a = dot2(wg[2][i], h0, b2a); b2b = dot2(wg[2][i], h1, b2b);
            b3a = dot2(wg[3][i], h0, b3a); b3b = dot2(wg[3][i], h1, b3b);
            b4a = dot2(wg[4][i], h0, b4a); b4b = dot2(wg[4][i], h1, b4b);
        }
        pB[kq][0][0][lane] = b0a; pB[kq][0][1][lane] = b1a; pB[kq][0][2][lane] = b2a;
        pB[kq][0][3][lane] = b3a; pB[kq][0][4][lane] = b4a;
        pB[kq][1][0][lane] = b0b; pB[kq][1][1][lane] = b1b; pB[kq][1][2][lane] = b2b;
        pB[kq][1][3][lane] = b3b; pB[kq][1][4][lane] = b4b;
        __syncthreads();
        // (6) cell update (tid<256)
        if (tid < 256) {
            float ai = pB[0][s][0][l] + pB[1][s][0][l] + pB[2][s][0][l] + pB[3][s][0][l] + xgg0;
            float af = pB[0][s][1][l] + pB[1][s][1][l] + pB[2][s][1][l] + pB[3][s][1][l] + xgg1;
            float ad = pB[0][s][2][l] + pB[1][s][2][l] + pB[2][s][2][l] + pB[3][s][2][l] + xgg2;
            float ag = pB[0][s][3][l] + pB[1][s][3][l] + pB[2][s][3][l] + pB[3][s][3][l] + xgg3;
            float ao = pB[0][s][4][l] + pB[1][s][4][l] + pB[2][s][4][l] + pB[3][s][4][l] + xgg4;
            float ig = fast_sig(ai);
            float fg = fast_sig(af);
            float dl = __expf(ad);
            float gt = tanhf(ag);
            float og = fast_sig(ao);
            float gc = fmaf(fg, cst, ig * gt);
            float df = cst - gc;
            float dtv = dt_time[row0 + s];
            cst = fmaf(df, __expf(-dl * dtv), gc);
            float hn = og * tanhf(cst);
            size_t go = (size_t)(row0 + s) * 512 + e * 128 + l;
            Gst[0 * GST_PLANE + go] = gc;
            Gst[1 * GST_PLANE + go] = df;
            Gst[2 * GST_PLANE + go] = dl;
            Gst[3 * GST_PLANE + go] = og;
            float hi = __shfl_down(hn, 1, 64);
            if ((l & 1) == 0) hOut[s * 64 + (l >> 1)] = pack2h(hn, hi);
            float lm = av * hn;
            #pragma unroll
            for (int off = 32; off > 0; off >>= 1) lm += __shfl_down(lm, off, 64);
            if ((tid & 63) == 0) red[tid >> 6] = lm;
        }
        __syncthreads();   // hOut/red ready; vmcnt drained per wave
        if (tid == 0) {
            lam_out[(row0 + 0) * 4 + e] = red[0] + red[1];
            lam_out[(row0 + 1) * 4 + e] = red[2] + red[3];
        }
        // (7) publish h to the other 3 consumers' copies (data IS the flag)
        {
            const int copy = tid >> 7;
            if (copy != e) {
                unsigned* dst = hbuf
                    + ((size_t)(((t + 1) & 1) * 64 + grp) * 4 + copy) * 512
                    + e * 128 + (tid & 127);
                __hip_atomic_store(dst, hOut[tid & 127], __ATOMIC_RELAXED,
                                   __HIP_MEMORY_SCOPE_AGENT);
            }
        }
    }
}

// ---------------- K3: trapezoid integrals, 1 block per (t,b); 8 ILP chains/thread ----------------
__global__ __launch_bounds__(256) void k3_trap(
    const float* __restrict__ Gst, const float* __restrict__ dt_time,
    const float* __restrict__ alpha, float* __restrict__ integ_out)
{
    __shared__ float red[4][2];
    const int row = blockIdx.x;
    const int tid = threadIdx.x;
    const float dtv = dt_time[row];
    const int base = row * 512;
    float acc[2];
    #pragma unroll
    for (int u = 0; u < 2; ++u) {
        const int p = tid + u * 256;
        float gc = Gst[0 * GST_PLANE + base + p];
        float df = Gst[1 * GST_PLANE + base + p];
        float dl = Gst[2 * GST_PLANE + base + p];
        float o  = Gst[3 * GST_PLANE + base + p];
        float ao = alpha[p] * o;
        float g2 = 2.f * gc, d2 = 2.f * df;
        float q  = dl * dtv;
        float r1 = __expf(-q * 0.01f);
        float r2 = r1 * r1, r4 = r2 * r2;
        float E100 = __expf(-q);
        float sE = 0.5f * sigt(g2 + d2) - 0.5f * sigt(fmaf(d2, E100, g2));
        float E1 = r1, E2 = r2, E3 = r2 * r1, E4 = r4;
        float s1 = 0.f, s2 = 0.f, s3 = 0.f, s4 = 0.f;
        #pragma unroll
        for (int k = 0; k < 25; ++k) {      // covers k=1..100
            s1 += sigt(fmaf(d2, E1, g2)); E1 *= r4;
            s2 += sigt(fmaf(d2, E2, g2)); E2 *= r4;
            s3 += sigt(fmaf(d2, E3, g2)); E3 *= r4;
            s4 += sigt(fmaf(d2, E4, g2)); E4 *= r4;
        }
        sE += (s1 + s2) + (s3 + s4);
        acc[u] = ao * (100.f - 2.f * sE);
    }
    float vA = acc[0], vB = acc[1];
    #pragma unroll
    for (int off = 32; off > 0; off >>= 1) {
        vA += __shfl_down(vA, off, 64);
        vB += __shfl_down(vB, off, 64);
    }
    const int wv = tid >> 6;
    if ((tid & 63) == 0) { red[wv][0] = vA; red[wv][1] = vB; }
    __syncthreads();
    if (tid < 4) {
        float v = (tid < 2) ? (red[2 * tid][0] + red[2 * tid + 1][0])
                            : (red[2 * (tid - 2)][1] + red[2 * (tid - 2) + 1][1]);
        integ_out[row * 4 + tid] = v * (dtv * 0.01f);
    }
}

extern "C" void kernel_launch(void* const* d_in, const int* in_sizes, int n_in,
                              void* d_out, int out_size, void* d_ws, size_t ws_size,
                              hipStream_t stream)
{
    const float* x_time  = (const float*)d_in[0];
    const float* dt_time = (const float*)d_in[1];
    const float* Wh_w = (const float*)d_in[2];
    const float* Wh_b = (const float*)d_in[3];
    const float* Wi_w = (const float*)d_in[4];
    const float* Wi_b = (const float*)d_in[5];
    const float* Wf_w = (const float*)d_in[6];
    const float* Wf_b = (const float*)d_in[7];
    const float* Wd_w = (const float*)d_in[8];
    const float* Wd_b = (const float*)d_in[9];
    const float* Wg_w = (const float*)d_in[10];
    const float* Wg_b = (const float*)d_in[11];
    const float* Wo_w = (const float*)d_in[12];
    const float* Wo_b = (const float*)d_in[13];
    const float* alpha = (const float*)d_in[14];

    float* ws = (float*)d_ws;
    float* XG   = ws + OFF_XG;
    float* Gst  = ws + OFF_GST;
    unsigned* hbuf = (unsigned*)(ws + OFF_HBUF);
    float* lam_out   = (float*)d_out;
    float* integ_out = lam_out + 32 * 128 * 4;

    k0_pack<<<3072, 256, 0, stream>>>(Wh_w, Wh_b, Wi_w, Wi_b, Wf_w, Wf_b,
                                      Wd_w, Wd_b, Wg_w, Wg_b, Wo_w, Wo_b, ws);
    k1_xproj<<<3072, 256, 0, stream>>>(x_time, ws, XG);
    k2_recur<<<256, 512, 0, stream>>>(
        (const uint4*)(ws + OFF_WHHH), (const unsigned*)(ws + OFF_WGH),
        XG, dt_time, alpha, Gst, hbuf, lam_out);
    k3_trap<<<4096, 256, 0, stream>>>(Gst, dt_time, alpha, integ_out);
}

// Round 12
// 239.790 us; speedup vs baseline: 1.2350x; 1.1439x over previous
//
#include <hip/hip_runtime.h>

// stackCLSTM: T=32, B=128, I=64, H=128, E=4, N_TRAP=100
// ws layout (float-word offsets):
//   W_all  [64][3072] fp32        @ 0         (196608)
//   bias   [3072] fp32            @ 196608    (3072)
//   WhhH   [e][kq][i4][lane][q]   @ 199680    (131072)  fp16-pair packed Whh h-part (uint4 rows)
//   WgH    [e][kq][16][5][128] u32@ 330752    (163840)  fp16-pair packed gate h-part
//   XG     [4096][3072] fp32      @ 494592    (12582912)
//   Gst    [4][4096*512] fp32     @ 13077504  (8388608)
//   hbuf   [2][64][4 copy][512] u32 @ 21466112 (262144) data-as-flag h exchange (sentinel 0xFFFFFFFF)
#define OFF_WALL   0
#define OFF_BIAS   196608
#define OFF_WHHH   199680
#define OFF_WGH    330752
#define OFF_XG     494592
#define OFF_GST    13077504
#define OFF_HBUF   21466112
#define GST_PLANE  2097152
#define H_SENT     0xFFFFFFFFu

typedef _Float16 half2_t __attribute__((ext_vector_type(2)));

__device__ __forceinline__ float fast_sig(float x) {
    return __fdividef(1.f, 1.f + __expf(-x));
}
__device__ __forceinline__ float sig2(float y2) {   // 1/(2^y2 + 1)
    return __builtin_amdgcn_rcpf(exp2f(y2) + 1.f);
}
__device__ __forceinline__ unsigned pack2h(float a, float b) {
    _Float16 ha = (_Float16)a, hb = (_Float16)b;
    unsigned short ua = __builtin_bit_cast(unsigned short, ha);
    unsigned short ub = __builtin_bit_cast(unsigned short, hb);
    return ((unsigned)ub << 16) | ua;
}
__device__ __forceinline__ float dot2(unsigned w, unsigned h, float acc) {
    return __builtin_amdgcn_fdot2(__builtin_bit_cast(half2_t, w),
                                  __builtin_bit_cast(half2_t, h), acc, false);
}

// ---------------- K0: pack weights + sentinel-fill hbuf ----------------
__global__ __launch_bounds__(256) void k0_pack(
    const float* __restrict__ Wh_w, const float* __restrict__ Wh_b,
    const float* __restrict__ Wi_w, const float* __restrict__ Wi_b,
    const float* __restrict__ Wf_w, const float* __restrict__ Wf_b,
    const float* __restrict__ Wd_w, const float* __restrict__ Wd_b,
    const float* __restrict__ Wg_w, const float* __restrict__ Wg_b,
    const float* __restrict__ Wo_w, const float* __restrict__ Wo_b,
    float* __restrict__ ws)
{
    const float* gw[5] = {Wi_w, Wf_w, Wd_w, Wg_w, Wo_w};
    const float* gb[5] = {Wi_b, Wf_b, Wd_b, Wg_b, Wo_b};
    int idx = blockIdx.x * 256 + threadIdx.x;
    if (idx < 196608) {            // W_all [r<64][col<3072]
        int r = idx / 3072, col = idx - r * 3072;
        float v;
        if (col < 512) {
            v = Wh_w[r * 512 + col] + Wh_w[(192 + r) * 512 + col]
              + Wh_w[(384 + r) * 512 + col] + Wh_w[(576 + r) * 512 + col];
        } else {
            int q = col - 512;
            int e = q / 640;
            int rem = q - e * 640;
            int g = rem >> 7, h = rem & 127;
            v = gw[g][(e * 192 + r) * 128 + h];
        }
        ws[OFF_WALL + idx] = v;
    } else if (idx < 327680) {     // WhhH [e][kq][i4][lane][q]  (uint4-per-lane rows)
        int i = idx - 196608;
        int q    = i & 3;
        int lane = (i >> 2) & 127;
        int i4   = (i >> 9) & 15;
        int kq   = (i >> 13) & 3;
        int e    = i >> 15;
        int kp = i4 * 4 + q;
        int k0 = kq * 128 + 2 * kp;
        int r0 = (k0 >> 7) * 192 + 64 + (k0 & 127);
        float w0 = Wh_w[r0 * 512 + e * 128 + lane];
        float w1 = Wh_w[(r0 + 1) * 512 + e * 128 + lane];
        reinterpret_cast<unsigned*>(ws + OFF_WHHH)[i] = pack2h(w0, w1);
    } else if (idx < 491520) {     // WgH [e][kq][16 ii][5 g][128 lane]
        int i = idx - 327680;
        int lane = i & 127;
        int gg = (i >> 7) % 5;
        int rest = (i >> 7) / 5;
        int ii = rest & 15;
        int kq = (rest >> 4) & 3;
        int e  = rest >> 6;
        int k0 = kq * 32 + 2 * ii, k1 = k0 + 1;
        float w0 = gw[gg][(e * 192 + 64 + k0) * 128 + lane];
        float w1 = gw[gg][(e * 192 + 64 + k1) * 128 + lane];
        reinterpret_cast<unsigned*>(ws + OFF_WGH)[i] = pack2h(w0, w1);
    }
    if (idx < 3072) {              // bias
        float v;
        if (idx < 512) v = Wh_b[idx];
        else {
            int q = idx - 512;
            int e = q / 640;
            int rem = q - e * 640;
            int g = rem >> 7, h = rem & 127;
            v = gb[g][e * 128 + h];
        }
        ws[OFF_BIAS + idx] = v;
    }
    if (idx < 262144) {            // sentinel-fill hbuf every launch (graph-replay safe)
        reinterpret_cast<unsigned*>(ws + OFF_HBUF)[idx] = H_SENT;
    }
}

// ---------------- K1: XG[4096][3072] = X[4096][64] @ W_all + bias ----------------
__global__ __launch_bounds__(256) void k1_xproj(
    const float* __restrict__ x, const float* wsr, float* XG)
{
    __shared__ __align__(16) float XT[64 * 68];
    const float* W_all = wsr + OFF_WALL;
    const float* bias  = wsr + OFF_BIAS;
    int bid = blockIdx.x;
    int ct = bid % 48, rt = bid / 48;
    int r0 = rt * 64, c0 = ct * 64;
    for (int p = threadIdx.x; p < 4096; p += 256) {
        int i = p >> 6, k = p & 63;
        XT[k * 68 + i] = x[(r0 + i) * 64 + k];
    }
    __syncthreads();
    int col = c0 + (threadIdx.x & 63);
    int iq = threadIdx.x >> 6;
    float acc[16];
    #pragma unroll
    for (int r = 0; r < 16; r++) acc[r] = 0.f;
    const float* wp = W_all + col;
    #pragma unroll 4
    for (int k = 0; k < 64; k++) {
        float w = wp[k * 3072];
        const float4* xt4 = reinterpret_cast<const float4*>(&XT[k * 68 + iq * 16]);
        #pragma unroll
        for (int r4 = 0; r4 < 4; r4++) {
            float4 xv = xt4[r4];
            acc[r4 * 4 + 0] = fmaf(xv.x, w, acc[r4 * 4 + 0]);
            acc[r4 * 4 + 1] = fmaf(xv.y, w, acc[r4 * 4 + 1]);
            acc[r4 * 4 + 2] = fmaf(xv.z, w, acc[r4 * 4 + 2]);
            acc[r4 * 4 + 3] = fmaf(xv.w, w, acc[r4 * 4 + 3]);
        }
    }
    float bv = bias[col];
    #pragma unroll
    for (int r = 0; r < 16; r++) {
        int row = r0 + iq * 16 + r;
        XG[row * 3072 + col] = acc[r] + bv;
    }
}

// ---------------- K2: recurrence; readlane broadcasts instead of LDS broadcast reads ----
// 256 blocks x 512 threads, 1 block/CU. Group of 4 (one per e) = 1 batch pair.
// Whh in LDS (b128-streamed once/step); h and hs broadcast via per-lane load +
// v_readlane (VALU pipes) instead of 64x ds_read broadcasts (single LDS pipe).
__global__ __launch_bounds__(512, 1) void k2_recur(
    const uint4* __restrict__ WhhH4,
    const unsigned* __restrict__ WgH,
    const float* __restrict__ XG,
    const float* __restrict__ dt_time,
    const float* __restrict__ alpha,
    float* __restrict__ Gst,
    unsigned* __restrict__ hbuf,
    float* __restrict__ lam_out)
{
    __shared__ __align__(16) uint4 waL[8192];       // 128 KB
    __shared__ __align__(16) unsigned hL[256][2];   // [pair][slot]
    __shared__ __align__(16) unsigned hsP[2][64];   // hs packed pairs [slot][pair]
    __shared__ __align__(16) unsigned hOut[128];    // this block's packed h (persists)
    __shared__ float pA[4][2][128];
    __shared__ __align__(16) float pBn[4][2][128][6];  // [kq][s][l][g0..g4,pad]
    __shared__ float red[4];
    const int tid = threadIdx.x;
    const int bid = blockIdx.x;
    const int e   = (bid >> 3) & 3;
    const int grp = (bid & 7) | ((bid >> 5) << 3);
    const int b0  = grp * 2;
    const int kq  = tid >> 7;
    const int lane = tid & 127;
    const int l64 = tid & 63;
    const int s = (tid >> 7) & 1, l = lane;

    // stage Whh e-slice into LDS (once)
    {
        const uint4* src = WhhH4 + (size_t)e * 8192;
        #pragma unroll
        for (int n = 0; n < 16; ++n) waL[tid + 512 * n] = src[tid + 512 * n];
    }
    unsigned wg[5][16];
    #pragma unroll
    for (int i = 0; i < 16; i++) {
        #pragma unroll
        for (int g = 0; g < 5; g++)
            wg[g][i] = WgH[(((e * 4 + kq) * 16 + i) * 5 + g) * 128 + lane];
    }
    const float av = alpha[e * 128 + lane];
    float cst = 0.f;
    __syncthreads();   // waL ready

    for (int t = 0; t < 32; ++t) {
        const int row0 = t * 128 + b0;
        // (1) XG prefetch
        float xg0 = 0.f, xgg0 = 0.f, xgg1 = 0.f, xgg2 = 0.f, xgg3 = 0.f, xgg4 = 0.f;
        if (tid < 256) {
            const float* base = XG + (size_t)(row0 + s) * 3072;
            xg0 = base[e * 128 + l];
            const float* gp = base + 512 + e * 640 + l;
            xgg0 = gp[0]; xgg1 = gp[128]; xgg2 = gp[256]; xgg3 = gp[384]; xgg4 = gp[512];
        }
        if (t > 0) {
            // (2+3) single-round-trip h acquire: data-as-flag, own slice from LDS
            {
                const int eh = tid >> 7, sh = (tid >> 6) & 1, p = tid & 63;
                unsigned v;
                if (eh == e) {
                    v = hOut[tid & 127];
                } else {
                    unsigned* ap = hbuf + ((size_t)((t & 1) * 64 + grp) * 4 + e) * 512 + tid;
                    v = __hip_atomic_load(ap, __ATOMIC_RELAXED, __HIP_MEMORY_SCOPE_AGENT);
                    while (v == H_SENT) {
                        __builtin_amdgcn_s_sleep(1);
                        v = __hip_atomic_load(ap, __ATOMIC_RELAXED, __HIP_MEMORY_SCOPE_AGENT);
                    }
                    __hip_atomic_store(ap, H_SENT, __ATOMIC_RELAXED,
                                       __HIP_MEMORY_SCOPE_AGENT);   // re-arm
                }
                hL[eh * 64 + p][sh] = v;
            }
            __syncthreads();
            // (4) phase A: per-lane h load + readlane broadcast (VALU, not LDS pipe)
            float a0 = 0.f, a1 = 0.f;
            {
                uint2 hu = reinterpret_cast<const uint2*>(hL)[kq * 64 + l64];
                #pragma unroll
                for (int i4 = 0; i4 < 16; ++i4) {
                    uint4 w = waL[(kq * 16 + i4) * 128 + lane];
                    unsigned h0, h1;
                    h0 = __builtin_amdgcn_readlane(hu.x, i4 * 4 + 0);
                    h1 = __builtin_amdgcn_readlane(hu.y, i4 * 4 + 0);
                    a0 = dot2(w.x, h0, a0); a1 = dot2(w.x, h1, a1);
                    h0 = __builtin_amdgcn_readlane(hu.x, i4 * 4 + 1);
                    h1 = __builtin_amdgcn_readlane(hu.y, i4 * 4 + 1);
                    a0 = dot2(w.y, h0, a0); a1 = dot2(w.y, h1, a1);
                    h0 = __builtin_amdgcn_readlane(hu.x, i4 * 4 + 2);
                    h1 = __builtin_amdgcn_readlane(hu.y, i4 * 4 + 2);
                    a0 = dot2(w.z, h0, a0); a1 = dot2(w.z, h1, a1);
                    h0 = __builtin_amdgcn_readlane(hu.x, i4 * 4 + 3);
                    h1 = __builtin_amdgcn_readlane(hu.y, i4 * 4 + 3);
                    a0 = dot2(w.w, h0, a0); a1 = dot2(w.w, h1, a1);
                }
            }
            pA[kq][0][lane] = a0;
            pA[kq][1][lane] = a1;
            __syncthreads();
        }
        if (tid < 256) {
            float hs = xg0;
            if (t > 0) hs += pA[0][s][l] + pA[1][s][l] + pA[2][s][l] + pA[3][s][l];
            float hi = __shfl_down(hs, 1, 64);
            if ((l & 1) == 0) hsP[s][l >> 1] = pack2h(hs, hi);
        }
        __syncthreads();   // hsP ready
        // (5) phase B: per-lane hs load + readlane broadcast
        float b0a = 0.f, b1a = 0.f, b2a = 0.f, b3a = 0.f, b4a = 0.f;
        float b0b = 0.f, b1b = 0.f, b2b = 0.f, b3b = 0.f, b4b = 0.f;
        {
            unsigned hv = hsP[(l64 >> 4) & 1][kq * 16 + (l64 & 15)];
            #pragma unroll
            for (int i = 0; i < 16; ++i) {
                unsigned h0 = __builtin_amdgcn_readlane(hv, i);
                unsigned h1 = __builtin_amdgcn_readlane(hv, 16 + i);
                b0a = dot2(wg[0][i], h0, b0a); b0b = dot2(wg[0][i], h1, b0b);
                b1a = dot2(wg[1][i], h0, b1a); b1b = dot2(wg[1][i], h1, b1b);
                b2a = dot2(wg[2][i], h0, b2a); b2b = dot2(wg[2][i], h1, b2b);
                b3a = dot2(wg[3][i], h0, b3a); b3b = dot2(wg[3][i], h1, b3b);
                b4a = dot2(wg[4][i], h0, b4a); b4b = dot2(wg[4][i], h1, b4b);
            }
        }
        {
            float2 w01, w23;
            w01.x = b0a; w01.y = b1a; w23.x = b2a; w23.y = b3a;
            *reinterpret_cast<float2*>(&pBn[kq][0][lane][0]) = w01;
            *reinterpret_cast<float2*>(&pBn[kq][0][lane][2]) = w23;
            pBn[kq][0][lane][4] = b4a;
            w01.x = b0b; w01.y = b1b; w23.x = b2b; w23.y = b3b;
            *reinterpret_cast<float2*>(&pBn[kq][1][lane][0]) = w01;
            *reinterpret_cast<float2*>(&pBn[kq][1][lane][2]) = w23;
            pBn[kq][1][lane][4] = b4b;
        }
        __syncthreads();
        // (6) cell update (tid<256)
        if (tid < 256) {
            float ai = xgg0, af = xgg1, ad = xgg2, ag = xgg3, ao = xgg4;
            #pragma unroll
            for (int q = 0; q < 4; ++q) {
                float2 p01 = *reinterpret_cast<const float2*>(&pBn[q][s][l][0]);
                float2 p23 = *reinterpret_cast<const float2*>(&pBn[q][s][l][2]);
                float p4 = pBn[q][s][l][4];
                ai += p01.x; af += p01.y; ad += p23.x; ag += p23.y; ao += p4;
            }
            float ig = fast_sig(ai);
            float fg = fast_sig(af);
            float dl = __expf(ad);
            float gt = tanhf(ag);
            float og = fast_sig(ao);
            float gc = fmaf(fg, cst, ig * gt);
            float df = cst - gc;
            float dtv = dt_time[row0 + s];
            cst = fmaf(df, __expf(-dl * dtv), gc);
            float hn = og * tanhf(cst);
            size_t go = (size_t)(row0 + s) * 512 + e * 128 + l;
            Gst[0 * GST_PLANE + go] = gc;
            Gst[1 * GST_PLANE + go] = df;
            Gst[2 * GST_PLANE + go] = dl;
            Gst[3 * GST_PLANE + go] = og;
            float hi = __shfl_down(hn, 1, 64);
            if ((l & 1) == 0) hOut[s * 64 + (l >> 1)] = pack2h(hn, hi);
            float lm = av * hn;
            #pragma unroll
            for (int off = 32; off > 0; off >>= 1) lm += __shfl_down(lm, off, 64);
            if ((tid & 63) == 0) red[tid >> 6] = lm;
        }
        __syncthreads();   // hOut/red ready
        if (tid == 0) {
            lam_out[(row0 + 0) * 4 + e] = red[0] + red[1];
            lam_out[(row0 + 1) * 4 + e] = red[2] + red[3];
        }
        // (7) publish h to the other 3 consumers' copies (data IS the flag)
        {
            const int copy = tid >> 7;
            if (copy != e) {
                unsigned* dst = hbuf
                    + ((size_t)(((t + 1) & 1) * 64 + grp) * 4 + copy) * 512
                    + e * 128 + (tid & 127);
                __hip_atomic_store(dst, hOut[tid & 127], __ATOMIC_RELAXED,
                                   __HIP_MEMORY_SCOPE_AGENT);
            }
        }
    }
}

// ---------------- K3: trapezoid; sequential elements, exp2/rcp sigt, 4 chains ----------------
__global__ __launch_bounds__(256) void k3_trap(
    const float* __restrict__ Gst, const float* __restrict__ dt_time,
    const float* __restrict__ alpha, float* __restrict__ integ_out)
{
    __shared__ float red[4][2];
    const int row = blockIdx.x;
    const int tid = threadIdx.x;
    const float dtv = dt_time[row];
    const int base = row * 512;
    const float L2E = 1.4426950408889634f;
    float accv[2];
    #pragma unroll 1
    for (int u = 0; u < 2; ++u) {
        const int p = tid + u * 256;
        float gc = Gst[0 * GST_PLANE + base + p];
        float df = Gst[1 * GST_PLANE + base + p];
        float dl = Gst[2 * GST_PLANE + base + p];
        float o  = Gst[3 * GST_PLANE + base + p];
        float ao = alpha[p] * o;
        float G = 2.f * gc * L2E, D = 2.f * df * L2E;   // fold log2e: e^y = 2^(G+D*E)
        float q  = dl * dtv;
        float r1 = exp2f(-q * (0.01f * L2E));
        float r2 = r1 * r1, r4 = r2 * r2;
        float E100 = exp2f(-q * L2E);
        float sE = 0.5f * sig2(G + D) - 0.5f * sig2(fmaf(D, E100, G));
        float E1 = r1, E2 = r2, E3 = r2 * r1, E4 = r4;
        float s1 = 0.f, s2 = 0.f, s3 = 0.f, s4 = 0.f;
        #pragma unroll
        for (int k = 0; k < 25; ++k) {      // chains cover k=1..100
            s1 += sig2(fmaf(D, E1, G)); E1 *= r4;
            s2 += sig2(fmaf(D, E2, G)); E2 *= r4;
            s3 += sig2(fmaf(D, E3, G)); E3 *= r4;
            s4 += sig2(fmaf(D, E4, G)); E4 *= r4;
        }
        sE += (s1 + s2) + (s3 + s4);
        accv[u] = ao * (100.f - 2.f * sE);
    }
    float vA = accv[0], vB = accv[1];
    #pragma unroll
    for (int off = 32; off > 0; off >>= 1) {
        vA += __shfl_down(vA, off, 64);
        vB += __shfl_down(vB, off, 64);
    }
    const int wv = tid >> 6;
    if ((tid & 63) == 0) { red[wv][0] = vA; red[wv][1] = vB; }
    __syncthreads();
    if (tid < 4) {
        float v = (tid < 2) ? (red[2 * tid][0] + red[2 * tid + 1][0])
                            : (red[2 * (tid - 2)][1] + red[2 * (tid - 2) + 1][1]);
        integ_out[row * 4 + tid] = v * (dtv * 0.01f);
    }
}

extern "C" void kernel_launch(void* const* d_in, const int* in_sizes, int n_in,
                              void* d_out, int out_size, void* d_ws, size_t ws_size,
                              hipStream_t stream)
{
    const float* x_time  = (const float*)d_in[0];
    const float* dt_time = (const float*)d_in[1];
    const float* Wh_w = (const float*)d_in[2];
    const float* Wh_b = (const float*)d_in[3];
    const float* Wi_w = (const float*)d_in[4];
    const float* Wi_b = (const float*)d_in[5];
    const float* Wf_w = (const float*)d_in[6];
    const float* Wf_b = (const float*)d_in[7];
    const float* Wd_w = (const float*)d_in[8];
    const float* Wd_b = (const float*)d_in[9];
    const float* Wg_w = (const float*)d_in[10];
    const float* Wg_b = (const float*)d_in[11];
    const float* Wo_w = (const float*)d_in[12];
    const float* Wo_b = (const float*)d_in[13];
    const float* alpha = (const float*)d_in[14];

    float* ws = (float*)d_ws;
    float* XG   = ws + OFF_XG;
    float* Gst  = ws + OFF_GST;
    unsigned* hbuf = (unsigned*)(ws + OFF_HBUF);
    float* lam_out   = (float*)d_out;
    float* integ_out = lam_out + 32 * 128 * 4;

    k0_pack<<<3072, 256, 0, stream>>>(Wh_w, Wh_b, Wi_w, Wi_b, Wf_w, Wf_b,
                                      Wd_w, Wd_b, Wg_w, Wg_b, Wo_w, Wo_b, ws);
    k1_xproj<<<3072, 256, 0, stream>>>(x_time, ws, XG);
    k2_recur<<<256, 512, 0, stream>>>(
        (const uint4*)(ws + OFF_WHHH), (const unsigned*)(ws + OFF_WGH),
        XG, dt_time, alpha, Gst, hbuf, lam_out);
    k3_trap<<<4096, 256, 0, stream>>>(Gst, dt_time, alpha, integ_out);
}

// Round 13
// 212.592 us; speedup vs baseline: 1.3930x; 1.1279x over previous
//
#include <hip/hip_runtime.h>

// stackCLSTM: T=32, B=128, I=64, H=128, E=4, N_TRAP=100
// ws layout (float-word offsets):
//   W_all  [64][3072] fp32        @ 0         (196608)
//   bias   [3072] fp32            @ 196608    (3072)
//   WhhH   [e][kq][i4][lane][q]   @ 199680    (131072)  fp16-pair packed Whh h-part (uint4 rows)
//   WgH    [e][kq][16][5][128] u32@ 330752    (163840)  fp16-pair packed gate h-part
//   XG     [4096][3072] fp32      @ 494592    (12582912)
//   Gst    [4][4096*512] fp32     @ 13077504  (8388608)
//   hbuf   [2][64][4 copy][256 pair][2 slot] u32 @ 21466112 (262144)
//          data-as-flag h exchange; 64-bit word per pair, sentinel ~0ull
#define OFF_WALL   0
#define OFF_BIAS   196608
#define OFF_WHHH   199680
#define OFF_WGH    330752
#define OFF_XG     494592
#define OFF_GST    13077504
#define OFF_HBUF   21466112
#define GST_PLANE  2097152

typedef _Float16 half2_t __attribute__((ext_vector_type(2)));

__device__ __forceinline__ float fast_sig(float x) {
    return __fdividef(1.f, 1.f + __expf(-x));
}
__device__ __forceinline__ float sig_e(float y) {   // 1/(e^y + 1), native exp+rcp
    return __builtin_amdgcn_rcpf(__expf(y) + 1.f);
}
__device__ __forceinline__ unsigned pack2h(float a, float b) {
    _Float16 ha = (_Float16)a, hb = (_Float16)b;
    unsigned short ua = __builtin_bit_cast(unsigned short, ha);
    unsigned short ub = __builtin_bit_cast(unsigned short, hb);
    return ((unsigned)ub << 16) | ua;
}
__device__ __forceinline__ float dot2(unsigned w, unsigned h, float acc) {
    return __builtin_amdgcn_fdot2(__builtin_bit_cast(half2_t, w),
                                  __builtin_bit_cast(half2_t, h), acc, false);
}

// ---------------- K0: pack weights + sentinel-fill hbuf ----------------
__global__ __launch_bounds__(256) void k0_pack(
    const float* __restrict__ Wh_w, const float* __restrict__ Wh_b,
    const float* __restrict__ Wi_w, const float* __restrict__ Wi_b,
    const float* __restrict__ Wf_w, const float* __restrict__ Wf_b,
    const float* __restrict__ Wd_w, const float* __restrict__ Wd_b,
    const float* __restrict__ Wg_w, const float* __restrict__ Wg_b,
    const float* __restrict__ Wo_w, const float* __restrict__ Wo_b,
    float* __restrict__ ws)
{
    const float* gw[5] = {Wi_w, Wf_w, Wd_w, Wg_w, Wo_w};
    const float* gb[5] = {Wi_b, Wf_b, Wd_b, Wg_b, Wo_b};
    int idx = blockIdx.x * 256 + threadIdx.x;
    if (idx < 196608) {            // W_all [r<64][col<3072]
        int r = idx / 3072, col = idx - r * 3072;
        float v;
        if (col < 512) {
            v = Wh_w[r * 512 + col] + Wh_w[(192 + r) * 512 + col]
              + Wh_w[(384 + r) * 512 + col] + Wh_w[(576 + r) * 512 + col];
        } else {
            int q = col - 512;
            int e = q / 640;
            int rem = q - e * 640;
            int g = rem >> 7, h = rem & 127;
            v = gw[g][(e * 192 + r) * 128 + h];
        }
        ws[OFF_WALL + idx] = v;
    } else if (idx < 327680) {     // WhhH [e][kq][i4][lane][q]  (uint4-per-lane rows)
        int i = idx - 196608;
        int q    = i & 3;
        int lane = (i >> 2) & 127;
        int i4   = (i >> 9) & 15;
        int kq   = (i >> 13) & 3;
        int e    = i >> 15;
        int kp = i4 * 4 + q;
        int k0 = kq * 128 + 2 * kp;
        int r0 = (k0 >> 7) * 192 + 64 + (k0 & 127);
        float w0 = Wh_w[r0 * 512 + e * 128 + lane];
        float w1 = Wh_w[(r0 + 1) * 512 + e * 128 + lane];
        reinterpret_cast<unsigned*>(ws + OFF_WHHH)[i] = pack2h(w0, w1);
    } else if (idx < 491520) {     // WgH [e][kq][16 ii][5 g][128 lane]
        int i = idx - 327680;
        int lane = i & 127;
        int gg = (i >> 7) % 5;
        int rest = (i >> 7) / 5;
        int ii = rest & 15;
        int kq = (rest >> 4) & 3;
        int e  = rest >> 6;
        int k0 = kq * 32 + 2 * ii, k1 = k0 + 1;
        float w0 = gw[gg][(e * 192 + 64 + k0) * 128 + lane];
        float w1 = gw[gg][(e * 192 + 64 + k1) * 128 + lane];
        reinterpret_cast<unsigned*>(ws + OFF_WGH)[i] = pack2h(w0, w1);
    }
    if (idx < 3072) {              // bias
        float v;
        if (idx < 512) v = Wh_b[idx];
        else {
            int q = idx - 512;
            int e = q / 640;
            int rem = q - e * 640;
            int g = rem >> 7, h = rem & 127;
            v = gb[g][e * 128 + h];
        }
        ws[OFF_BIAS + idx] = v;
    }
    if (idx < 262144) {            // sentinel-fill hbuf every launch (graph-replay safe)
        reinterpret_cast<unsigned*>(ws + OFF_HBUF)[idx] = 0xFFFFFFFFu;
    }
}

// ---------------- K1: XG[4096][3072] = X[4096][64] @ W_all + bias ----------------
__global__ __launch_bounds__(256) void k1_xproj(
    const float* __restrict__ x, const float* wsr, float* XG)
{
    __shared__ __align__(16) float XT[64 * 68];
    const float* W_all = wsr + OFF_WALL;
    const float* bias  = wsr + OFF_BIAS;
    int bid = blockIdx.x;
    int ct = bid % 48, rt = bid / 48;
    int r0 = rt * 64, c0 = ct * 64;
    for (int p = threadIdx.x; p < 4096; p += 256) {
        int i = p >> 6, k = p & 63;
        XT[k * 68 + i] = x[(r0 + i) * 64 + k];
    }
    __syncthreads();
    int col = c0 + (threadIdx.x & 63);
    int iq = threadIdx.x >> 6;
    float acc[16];
    #pragma unroll
    for (int r = 0; r < 16; r++) acc[r] = 0.f;
    const float* wp = W_all + col;
    #pragma unroll 4
    for (int k = 0; k < 64; k++) {
        float w = wp[k * 3072];
        const float4* xt4 = reinterpret_cast<const float4*>(&XT[k * 68 + iq * 16]);
        #pragma unroll
        for (int r4 = 0; r4 < 4; r4++) {
            float4 xv = xt4[r4];
            acc[r4 * 4 + 0] = fmaf(xv.x, w, acc[r4 * 4 + 0]);
            acc[r4 * 4 + 1] = fmaf(xv.y, w, acc[r4 * 4 + 1]);
            acc[r4 * 4 + 2] = fmaf(xv.z, w, acc[r4 * 4 + 2]);
            acc[r4 * 4 + 3] = fmaf(xv.w, w, acc[r4 * 4 + 3]);
        }
    }
    float bv = bias[col];
    #pragma unroll
    for (int r = 0; r < 16; r++) {
        int row = r0 + iq * 16 + r;
        XG[row * 3072 + col] = acc[r] + bv;
    }
}

// ---------------- K2: recurrence; per-thread 64-bit data-as-flag, no acquire barrier ----
// 256 blocks x 512 threads, 1 block/CU. Group of 4 (one per e) = 1 batch pair.
// Each phase-A thread polls exactly the ONE uint2 word it broadcasts (own-e from LDS).
// Re-arm deferred to after bar1 so both duplicate pollers (wave0/wave1) read first.
__global__ __launch_bounds__(512, 1) void k2_recur(
    const uint4* __restrict__ WhhH4,
    const unsigned* __restrict__ WgH,
    const float* __restrict__ XG,
    const float* __restrict__ dt_time,
    const float* __restrict__ alpha,
    float* __restrict__ Gst,
    unsigned* __restrict__ hbuf,
    float* __restrict__ lam_out)
{
    __shared__ __align__(16) uint4 waL[8192];       // 128 KB
    __shared__ __align__(16) unsigned hsP[2][64];   // hs packed pairs [slot][pair]
    __shared__ __align__(16) unsigned hOut[128];    // this block's packed h (persists)
    __shared__ float pA[4][2][128];
    __shared__ float pB[4][2][5][128];              // [kq][s][g][l] conflict-free
    __shared__ float red[4];
    const int tid = threadIdx.x;
    const int bid = blockIdx.x;
    const int e   = (bid >> 3) & 3;
    const int grp = (bid & 7) | ((bid >> 5) << 3);
    const int b0  = grp * 2;
    const int kq  = tid >> 7;
    const int lane = tid & 127;
    const int l64 = tid & 63;
    const int s = (tid >> 7) & 1, l = lane;

    // stage Whh e-slice into LDS (once)
    {
        const uint4* src = WhhH4 + (size_t)e * 8192;
        #pragma unroll
        for (int n = 0; n < 16; ++n) waL[tid + 512 * n] = src[tid + 512 * n];
    }
    unsigned wg[5][16];
    #pragma unroll
    for (int i = 0; i < 16; i++) {
        #pragma unroll
        for (int g = 0; g < 5; g++)
            wg[g][i] = WgH[(((e * 4 + kq) * 16 + i) * 5 + g) * 128 + lane];
    }
    const float av = alpha[e * 128 + lane];
    float cst = 0.f;
    __syncthreads();   // waL ready

    for (int t = 0; t < 32; ++t) {
        const int row0 = t * 128 + b0;
        // (1) XG prefetch
        float xg0 = 0.f, xgg0 = 0.f, xgg1 = 0.f, xgg2 = 0.f, xgg3 = 0.f, xgg4 = 0.f;
        if (tid < 256) {
            const float* base = XG + (size_t)(row0 + s) * 3072;
            xg0 = base[e * 128 + l];
            const float* gp = base + 512 + e * 640 + l;
            xgg0 = gp[0]; xgg1 = gp[128]; xgg2 = gp[256]; xgg3 = gp[384]; xgg4 = gp[512];
        }
        if (t > 0) {
            // (2) acquire the single uint2 this thread broadcasts from
            uint2 hu;
            if (kq == e) {
                hu.x = hOut[l64];
                hu.y = hOut[64 + l64];
            } else {
                const unsigned long long* ap =
                    reinterpret_cast<const unsigned long long*>(
                        hbuf + ((size_t)((t & 1) * 64 + grp) * 4 + e) * 512)
                    + (kq * 64 + l64);
                unsigned long long v = __hip_atomic_load(ap, __ATOMIC_RELAXED,
                                                         __HIP_MEMORY_SCOPE_AGENT);
                while (v == ~0ull) {
                    __builtin_amdgcn_s_sleep(1);
                    v = __hip_atomic_load(ap, __ATOMIC_RELAXED,
                                          __HIP_MEMORY_SCOPE_AGENT);
                }
                hu.x = (unsigned)v;
                hu.y = (unsigned)(v >> 32);
            }
            // (3) phase A: readlane broadcast dots (VALU)
            float a0 = 0.f, a1 = 0.f;
            #pragma unroll
            for (int i4 = 0; i4 < 16; ++i4) {
                uint4 w = waL[(kq * 16 + i4) * 128 + lane];
                unsigned h0, h1;
                h0 = __builtin_amdgcn_readlane(hu.x, i4 * 4 + 0);
                h1 = __builtin_amdgcn_readlane(hu.y, i4 * 4 + 0);
                a0 = dot2(w.x, h0, a0); a1 = dot2(w.x, h1, a1);
                h0 = __builtin_amdgcn_readlane(hu.x, i4 * 4 + 1);
                h1 = __builtin_amdgcn_readlane(hu.y, i4 * 4 + 1);
                a0 = dot2(w.y, h0, a0); a1 = dot2(w.y, h1, a1);
                h0 = __builtin_amdgcn_readlane(hu.x, i4 * 4 + 2);
                h1 = __builtin_amdgcn_readlane(hu.y, i4 * 4 + 2);
                a0 = dot2(w.z, h0, a0); a1 = dot2(w.z, h1, a1);
                h0 = __builtin_amdgcn_readlane(hu.x, i4 * 4 + 3);
                h1 = __builtin_amdgcn_readlane(hu.y, i4 * 4 + 3);
                a0 = dot2(w.w, h0, a0); a1 = dot2(w.w, h1, a1);
            }
            pA[kq][0][lane] = a0;
            pA[kq][1][lane] = a1;
        }
        __syncthreads();   // bar1: pA ready; both pollers of each word have read
        // re-arm polled words (one thread per word)
        if (t > 0 && kq != e && lane < 64) {
            unsigned long long* ap =
                reinterpret_cast<unsigned long long*>(
                    hbuf + ((size_t)((t & 1) * 64 + grp) * 4 + e) * 512)
                + (kq * 64 + l64);
            __hip_atomic_store(ap, ~0ull, __ATOMIC_RELAXED, __HIP_MEMORY_SCOPE_AGENT);
        }
        if (tid < 256) {
            float hs = xg0;
            if (t > 0) hs += pA[0][s][l] + pA[1][s][l] + pA[2][s][l] + pA[3][s][l];
            float hi = __shfl_down(hs, 1, 64);
            if ((l & 1) == 0) hsP[s][l >> 1] = pack2h(hs, hi);
        }
        __syncthreads();   // bar2: hsP ready
        // (5) phase B: readlane broadcast gate dots
        float b0a = 0.f, b1a = 0.f, b2a = 0.f, b3a = 0.f, b4a = 0.f;
        float b0b = 0.f, b1b = 0.f, b2b = 0.f, b3b = 0.f, b4b = 0.f;
        {
            unsigned hv = hsP[(l64 >> 4) & 1][kq * 16 + (l64 & 15)];
            #pragma unroll
            for (int i = 0; i < 16; ++i) {
                unsigned h0 = __builtin_amdgcn_readlane(hv, i);
                unsigned h1 = __builtin_amdgcn_readlane(hv, 16 + i);
                b0a = dot2(wg[0][i], h0, b0a); b0b = dot2(wg[0][i], h1, b0b);
                b1a = dot2(wg[1][i], h0, b1a); b1b = dot2(wg[1][i], h1, b1b);
                b2a = dot2(wg[2][i], h0, b2a); b2b = dot2(wg[2][i], h1, b2b);
                b3a = dot2(wg[3][i], h0, b3a); b3b = dot2(wg[3][i], h1, b3b);
                b4a = dot2(wg[4][i], h0, b4a); b4b = dot2(wg[4][i], h1, b4b);
            }
        }
        pB[kq][0][0][lane] = b0a; pB[kq][0][1][lane] = b1a; pB[kq][0][2][lane] = b2a;
        pB[kq][0][3][lane] = b3a; pB[kq][0][4][lane] = b4a;
        pB[kq][1][0][lane] = b0b; pB[kq][1][1][lane] = b1b; pB[kq][1][2][lane] = b2b;
        pB[kq][1][3][lane] = b3b; pB[kq][1][4][lane] = b4b;
        __syncthreads();   // bar3: pB ready
        // (6) cell update (tid<256)
        if (tid < 256) {
            float ai = pB[0][s][0][l] + pB[1][s][0][l] + pB[2][s][0][l] + pB[3][s][0][l] + xgg0;
            float af = pB[0][s][1][l] + pB[1][s][1][l] + pB[2][s][1][l] + pB[3][s][1][l] + xgg1;
            float ad = pB[0][s][2][l] + pB[1][s][2][l] + pB[2][s][2][l] + pB[3][s][2][l] + xgg2;
            float ag = pB[0][s][3][l] + pB[1][s][3][l] + pB[2][s][3][l] + pB[3][s][3][l] + xgg3;
            float ao = pB[0][s][4][l] + pB[1][s][4][l] + pB[2][s][4][l] + pB[3][s][4][l] + xgg4;
            float ig = fast_sig(ai);
            float fg = fast_sig(af);
            float dl = __expf(ad);
            float gt = tanhf(ag);
            float og = fast_sig(ao);
            float gc = fmaf(fg, cst, ig * gt);
            float df = cst - gc;
            float dtv = dt_time[row0 + s];
            cst = fmaf(df, __expf(-dl * dtv), gc);
            float hn = og * tanhf(cst);
            size_t go = (size_t)(row0 + s) * 512 + e * 128 + l;
            Gst[0 * GST_PLANE + go] = gc;
            Gst[1 * GST_PLANE + go] = df;
            Gst[2 * GST_PLANE + go] = dl;
            Gst[3 * GST_PLANE + go] = og;
            float hi = __shfl_down(hn, 1, 64);
            if ((l & 1) == 0) hOut[s * 64 + (l >> 1)] = pack2h(hn, hi);
            float lm = av * hn;
            #pragma unroll
            for (int off = 32; off > 0; off >>= 1) lm += __shfl_down(lm, off, 64);
            if ((tid & 63) == 0) red[tid >> 6] = lm;
        }
        __syncthreads();   // bar4: hOut/red ready; vmcnt drained (re-arm + Gst landed)
        if (tid == 0) {
            lam_out[(row0 + 0) * 4 + e] = red[0] + red[1];
            lam_out[(row0 + 1) * 4 + e] = red[2] + red[3];
        }
        // (7) publish: one 64-bit word per pair to each of 3 consumer copies
        if (tid < 192) {
            int cpy = tid >> 6;
            cpy += (cpy >= e) ? 1 : 0;
            int qp = tid & 63;
            unsigned long long v =
                ((unsigned long long)hOut[64 + qp] << 32) | (unsigned long long)hOut[qp];
            unsigned long long* dst =
                reinterpret_cast<unsigned long long*>(
                    hbuf + ((size_t)(((t + 1) & 1) * 64 + grp) * 4 + cpy) * 512)
                + (e * 64 + qp);
            __hip_atomic_store(dst, v, __ATOMIC_RELAXED, __HIP_MEMORY_SCOPE_AGENT);
        }
    }
}

// ---------------- K3: trapezoid; native exp, 8 interleaved chains ----------------
__global__ __launch_bounds__(256) void k3_trap(
    const float* __restrict__ Gst, const float* __restrict__ dt_time,
    const float* __restrict__ alpha, float* __restrict__ integ_out)
{
    __shared__ float red[4][2];
    const int row = blockIdx.x;
    const int tid = threadIdx.x;
    const float dtv = dt_time[row];
    const int base = row * 512;
    const int iA = tid, iB = tid + 256;
    float gcA = Gst[0 * GST_PLANE + base + iA];
    float gcB = Gst[0 * GST_PLANE + base + iB];
    float dfA = Gst[1 * GST_PLANE + base + iA];
    float dfB = Gst[1 * GST_PLANE + base + iB];
    float dlA = Gst[2 * GST_PLANE + base + iA];
    float dlB = Gst[2 * GST_PLANE + base + iB];
    float oA  = Gst[3 * GST_PLANE + base + iA];
    float oB  = Gst[3 * GST_PLANE + base + iB];
    float aoA = alpha[iA] * oA;
    float aoB = alpha[iB] * oB;
    float gA = 2.f * gcA, dA = 2.f * dfA;
    float gB = 2.f * gcB, dB = 2.f * dfB;
    float qA = dlA * dtv, qB = dlB * dtv;
    float r1A = __expf(-qA * 0.01f), r1B = __expf(-qB * 0.01f);
    float r2A = r1A * r1A, r2B = r1B * r1B;
    float r4A = r2A * r2A, r4B = r2B * r2B;
    float e100A = __expf(-qA), e100B = __expf(-qB);
    float sA = 0.5f * sig_e(gA + dA) - 0.5f * sig_e(fmaf(dA, e100A, gA));
    float sB = 0.5f * sig_e(gB + dB) - 0.5f * sig_e(fmaf(dB, e100B, gB));
    float E1A = r1A, E2A = r2A, E3A = r2A * r1A, E4A = r4A;
    float E1B = r1B, E2B = r2B, E3B = r2B * r1B, E4B = r4B;
    float s1A = 0.f, s2A = 0.f, s3A = 0.f, s4A = 0.f;
    float s1B = 0.f, s2B = 0.f, s3B = 0.f, s4B = 0.f;
    #pragma unroll
    for (int k = 0; k < 25; ++k) {      // chains cover k=1..100
        s1A += sig_e(fmaf(dA, E1A, gA)); E1A *= r4A;
        s1B += sig_e(fmaf(dB, E1B, gB)); E1B *= r4B;
        s2A += sig_e(fmaf(dA, E2A, gA)); E2A *= r4A;
        s2B += sig_e(fmaf(dB, E2B, gB)); E2B *= r4B;
        s3A += sig_e(fmaf(dA, E3A, gA)); E3A *= r4A;
        s3B += sig_e(fmaf(dB, E3B, gB)); E3B *= r4B;
        s4A += sig_e(fmaf(dA, E4A, gA)); E4A *= r4A;
        s4B += sig_e(fmaf(dB, E4B, gB)); E4B *= r4B;
    }
    sA += (s1A + s2A) + (s3A + s4A);
    sB += (s1B + s2B) + (s3B + s4B);
    float vA = aoA * (100.f - 2.f * sA);
    float vB = aoB * (100.f - 2.f * sB);
    #pragma unroll
    for (int off = 32; off > 0; off >>= 1) {
        vA += __shfl_down(vA, off, 64);
        vB += __shfl_down(vB, off, 64);
    }
    const int wv = tid >> 6;
    if ((tid & 63) == 0) { red[wv][0] = vA; red[wv][1] = vB; }
    __syncthreads();
    if (tid < 4) {
        float v = (tid < 2) ? (red[2 * tid][0] + red[2 * tid + 1][0])
                            : (red[2 * (tid - 2)][1] + red[2 * (tid - 2) + 1][1]);
        integ_out[row * 4 + tid] = v * (dtv * 0.01f);
    }
}

extern "C" void kernel_launch(void* const* d_in, const int* in_sizes, int n_in,
                              void* d_out, int out_size, void* d_ws, size_t ws_size,
                              hipStream_t stream)
{
    const float* x_time  = (const float*)d_in[0];
    const float* dt_time = (const float*)d_in[1];
    const float* Wh_w = (const float*)d_in[2];
    const float* Wh_b = (const float*)d_in[3];
    const float* Wi_w = (const float*)d_in[4];
    const float* Wi_b = (const float*)d_in[5];
    const float* Wf_w = (const float*)d_in[6];
    const float* Wf_b = (const float*)d_in[7];
    const float* Wd_w = (const float*)d_in[8];
    const float* Wd_b = (const float*)d_in[9];
    const float* Wg_w = (const float*)d_in[10];
    const float* Wg_b = (const float*)d_in[11];
    const float* Wo_w = (const float*)d_in[12];
    const float* Wo_b = (const float*)d_in[13];
    const float* alpha = (const float*)d_in[14];

    float* ws = (float*)d_ws;
    float* XG   = ws + OFF_XG;
    float* Gst  = ws + OFF_GST;
    unsigned* hbuf = (unsigned*)(ws + OFF_HBUF);
    float* lam_out   = (float*)d_out;
    float* integ_out = lam_out + 32 * 128 * 4;

    k0_pack<<<3072, 256, 0, stream>>>(Wh_w, Wh_b, Wi_w, Wi_b, Wf_w, Wf_b,
                                      Wd_w, Wd_b, Wg_w, Wg_b, Wo_w, Wo_b, ws);
    k1_xproj<<<3072, 256, 0, stream>>>(x_time, ws, XG);
    k2_recur<<<256, 512, 0, stream>>>(
        (const uint4*)(ws + OFF_WHHH), (const unsigned*)(ws + OFF_WGH),
        XG, dt_time, alpha, Gst, hbuf, lam_out);
    k3_trap<<<4096, 256, 0, stream>>>(Gst, dt_time, alpha, integ_out);
}

// Round 14
// 212.264 us; speedup vs baseline: 1.3952x; 1.0015x over previous
//
#include <hip/hip_runtime.h>

// stackCLSTM: T=32, B=128, I=64, H=128, E=4, N_TRAP=100
// ws layout (float-word offsets):
//   W_all  [64][3072] fp32        @ 0         (196608)
//   bias   [3072] fp32            @ 196608    (3072)
//   WhhH   [e][kq][i4][lane][q]   @ 199680    (131072)  fp16-pair packed Whh h-part (uint4 rows)
//   WgH    [e][kq][16][5][128] u32@ 330752    (163840)  fp16-pair packed gate h-part
//   XG     [4096][3072] fp32      @ 494592    (12582912)
//   hbuf   [2][64][4 copy][256 pair][2 slot] u32 @ 21466112 (262144)
//          data-as-flag h exchange; 64-bit word per pair, sentinel ~0ull
#define OFF_WALL   0
#define OFF_BIAS   196608
#define OFF_WHHH   199680
#define OFF_WGH    330752
#define OFF_XG     494592
#define OFF_HBUF   21466112

typedef _Float16 half2_t __attribute__((ext_vector_type(2)));

__device__ __forceinline__ float fast_sig(float x) {
    return __fdividef(1.f, 1.f + __expf(-x));
}
__device__ __forceinline__ float sig_e(float y) {   // 1/(e^y + 1), native exp+rcp
    return __builtin_amdgcn_rcpf(__expf(y) + 1.f);
}
__device__ __forceinline__ unsigned pack2h(float a, float b) {
    _Float16 ha = (_Float16)a, hb = (_Float16)b;
    unsigned short ua = __builtin_bit_cast(unsigned short, ha);
    unsigned short ub = __builtin_bit_cast(unsigned short, hb);
    return ((unsigned)ub << 16) | ua;
}
__device__ __forceinline__ float dot2(unsigned w, unsigned h, float acc) {
    return __builtin_amdgcn_fdot2(__builtin_bit_cast(half2_t, w),
                                  __builtin_bit_cast(half2_t, h), acc, false);
}

// ---------------- K0: pack weights + sentinel-fill hbuf ----------------
__global__ __launch_bounds__(256) void k0_pack(
    const float* __restrict__ Wh_w, const float* __restrict__ Wh_b,
    const float* __restrict__ Wi_w, const float* __restrict__ Wi_b,
    const float* __restrict__ Wf_w, const float* __restrict__ Wf_b,
    const float* __restrict__ Wd_w, const float* __restrict__ Wd_b,
    const float* __restrict__ Wg_w, const float* __restrict__ Wg_b,
    const float* __restrict__ Wo_w, const float* __restrict__ Wo_b,
    float* __restrict__ ws)
{
    const float* gw[5] = {Wi_w, Wf_w, Wd_w, Wg_w, Wo_w};
    const float* gb[5] = {Wi_b, Wf_b, Wd_b, Wg_b, Wo_b};
    int idx = blockIdx.x * 256 + threadIdx.x;
    if (idx < 196608) {            // W_all [r<64][col<3072]
        int r = idx / 3072, col = idx - r * 3072;
        float v;
        if (col < 512) {
            v = Wh_w[r * 512 + col] + Wh_w[(192 + r) * 512 + col]
              + Wh_w[(384 + r) * 512 + col] + Wh_w[(576 + r) * 512 + col];
        } else {
            int q = col - 512;
            int e = q / 640;
            int rem = q - e * 640;
            int g = rem >> 7, h = rem & 127;
            v = gw[g][(e * 192 + r) * 128 + h];
        }
        ws[OFF_WALL + idx] = v;
    } else if (idx < 327680) {     // WhhH [e][kq][i4][lane][q]  (uint4-per-lane rows)
        int i = idx - 196608;
        int q    = i & 3;
        int lane = (i >> 2) & 127;
        int i4   = (i >> 9) & 15;
        int kq   = (i >> 13) & 3;
        int e    = i >> 15;
        int kp = i4 * 4 + q;
        int k0 = kq * 128 + 2 * kp;
        int r0 = (k0 >> 7) * 192 + 64 + (k0 & 127);
        float w0 = Wh_w[r0 * 512 + e * 128 + lane];
        float w1 = Wh_w[(r0 + 1) * 512 + e * 128 + lane];
        reinterpret_cast<unsigned*>(ws + OFF_WHHH)[i] = pack2h(w0, w1);
    } else if (idx < 491520) {     // WgH [e][kq][16 ii][5 g][128 lane]
        int i = idx - 327680;
        int lane = i & 127;
        int gg = (i >> 7) % 5;
        int rest = (i >> 7) / 5;
        int ii = rest & 15;
        int kq = (rest >> 4) & 3;
        int e  = rest >> 6;
        int k0 = kq * 32 + 2 * ii, k1 = k0 + 1;
        float w0 = gw[gg][(e * 192 + 64 + k0) * 128 + lane];
        float w1 = gw[gg][(e * 192 + 64 + k1) * 128 + lane];
        reinterpret_cast<unsigned*>(ws + OFF_WGH)[i] = pack2h(w0, w1);
    }
    if (idx < 3072) {              // bias
        float v;
        if (idx < 512) v = Wh_b[idx];
        else {
            int q = idx - 512;
            int e = q / 640;
            int rem = q - e * 640;
            int g = rem >> 7, h = rem & 127;
            v = gb[g][e * 128 + h];
        }
        ws[OFF_BIAS + idx] = v;
    }
    if (idx < 262144) {            // sentinel-fill hbuf every launch (graph-replay safe)
        reinterpret_cast<unsigned*>(ws + OFF_HBUF)[idx] = 0xFFFFFFFFu;
    }
}

// ---------------- K1: XG[4096][3072] = X[4096][64] @ W_all + bias ----------------
__global__ __launch_bounds__(256) void k1_xproj(
    const float* __restrict__ x, const float* wsr, float* XG)
{
    __shared__ __align__(16) float XT[64 * 68];
    const float* W_all = wsr + OFF_WALL;
    const float* bias  = wsr + OFF_BIAS;
    int bid = blockIdx.x;
    int ct = bid % 48, rt = bid / 48;
    int r0 = rt * 64, c0 = ct * 64;
    for (int p = threadIdx.x; p < 4096; p += 256) {
        int i = p >> 6, k = p & 63;
        XT[k * 68 + i] = x[(r0 + i) * 64 + k];
    }
    __syncthreads();
    int col = c0 + (threadIdx.x & 63);
    int iq = threadIdx.x >> 6;
    float acc[16];
    #pragma unroll
    for (int r = 0; r < 16; r++) acc[r] = 0.f;
    const float* wp = W_all + col;
    #pragma unroll 4
    for (int k = 0; k < 64; k++) {
        float w = wp[k * 3072];
        const float4* xt4 = reinterpret_cast<const float4*>(&XT[k * 68 + iq * 16]);
        #pragma unroll
        for (int r4 = 0; r4 < 4; r4++) {
            float4 xv = xt4[r4];
            acc[r4 * 4 + 0] = fmaf(xv.x, w, acc[r4 * 4 + 0]);
            acc[r4 * 4 + 1] = fmaf(xv.y, w, acc[r4 * 4 + 1]);
            acc[r4 * 4 + 2] = fmaf(xv.z, w, acc[r4 * 4 + 2]);
            acc[r4 * 4 + 3] = fmaf(xv.w, w, acc[r4 * 4 + 3]);
        }
    }
    float bv = bias[col];
    #pragma unroll
    for (int r = 0; r < 16; r++) {
        int row = r0 + iq * 16 + r;
        XG[row * 3072 + col] = acc[r] + bv;
    }
}

// ---------------- K2: recurrence + trapezoid fused into the sync window ----------------
// 256 blocks x 512 threads, 1 block/CU. Group of 4 (one per e) = 1 batch pair.
// After publishing h, all 512 threads compute the step's trapezoid integral
// (tuple split: tid<256 does k=0..48, tid>=256 does k=49..100; 4 geometric chains
// each). This work sits exactly in the publish->poll IC-latency window, so the
// next step's poll finds data already visible. k3 kernel and Gst traffic deleted.
__global__ __launch_bounds__(512, 1) void k2_recur(
    const uint4* __restrict__ WhhH4,
    const unsigned* __restrict__ WgH,
    const float* __restrict__ XG,
    const float* __restrict__ dt_time,
    const float* __restrict__ alpha,
    unsigned* __restrict__ hbuf,
    float* __restrict__ lam_out,
    float* __restrict__ integ_out)
{
    __shared__ __align__(16) uint4 waL[8192];       // 128 KB
    __shared__ __align__(16) unsigned hsP[2][64];   // hs packed pairs [slot][pair]
    __shared__ __align__(16) unsigned hOut[128];    // this block's packed h (persists)
    __shared__ float pA[4][2][128];
    __shared__ float pB[4][2][5][128];              // [kq][s][g][l] conflict-free
    __shared__ __align__(16) float4 cellSt[256];    // {2g, 2d, dl*dt, av*og} per tuple
    __shared__ float red[4];
    __shared__ float red2[8];
    const int tid = threadIdx.x;
    const int bid = blockIdx.x;
    const int e   = (bid >> 3) & 3;
    const int grp = (bid & 7) | ((bid >> 5) << 3);
    const int b0  = grp * 2;
    const int kq  = tid >> 7;
    const int lane = tid & 127;
    const int l64 = tid & 63;
    const int s = (tid >> 7) & 1, l = lane;

    // stage Whh e-slice into LDS (once)
    {
        const uint4* src = WhhH4 + (size_t)e * 8192;
        #pragma unroll
        for (int n = 0; n < 16; ++n) waL[tid + 512 * n] = src[tid + 512 * n];
    }
    unsigned wg[5][16];
    #pragma unroll
    for (int i = 0; i < 16; i++) {
        #pragma unroll
        for (int g = 0; g < 5; g++)
            wg[g][i] = WgH[(((e * 4 + kq) * 16 + i) * 5 + g) * 128 + lane];
    }
    const float av = alpha[e * 128 + lane];
    float cst = 0.f;
    __syncthreads();   // waL ready

    for (int t = 0; t < 32; ++t) {
        const int row0 = t * 128 + b0;
        // (1) XG prefetch
        float xg0 = 0.f, xgg0 = 0.f, xgg1 = 0.f, xgg2 = 0.f, xgg3 = 0.f, xgg4 = 0.f;
        if (tid < 256) {
            const float* base = XG + (size_t)(row0 + s) * 3072;
            xg0 = base[e * 128 + l];
            const float* gp = base + 512 + e * 640 + l;
            xgg0 = gp[0]; xgg1 = gp[128]; xgg2 = gp[256]; xgg3 = gp[384]; xgg4 = gp[512];
        }
        if (t > 0) {
            // (2) acquire the single uint2 this thread broadcasts from
            uint2 hu;
            if (kq == e) {
                hu.x = hOut[l64];
                hu.y = hOut[64 + l64];
            } else {
                const unsigned long long* ap =
                    reinterpret_cast<const unsigned long long*>(
                        hbuf + ((size_t)((t & 1) * 64 + grp) * 4 + e) * 512)
                    + (kq * 64 + l64);
                unsigned long long v = __hip_atomic_load(ap, __ATOMIC_RELAXED,
                                                         __HIP_MEMORY_SCOPE_AGENT);
                while (v == ~0ull) {
                    __builtin_amdgcn_s_sleep(1);
                    v = __hip_atomic_load(ap, __ATOMIC_RELAXED,
                                          __HIP_MEMORY_SCOPE_AGENT);
                }
                hu.x = (unsigned)v;
                hu.y = (unsigned)(v >> 32);
            }
            // (3) phase A: readlane broadcast dots (VALU)
            float a0 = 0.f, a1 = 0.f;
            #pragma unroll
            for (int i4 = 0; i4 < 16; ++i4) {
                uint4 w = waL[(kq * 16 + i4) * 128 + lane];
                unsigned h0, h1;
                h0 = __builtin_amdgcn_readlane(hu.x, i4 * 4 + 0);
                h1 = __builtin_amdgcn_readlane(hu.y, i4 * 4 + 0);
                a0 = dot2(w.x, h0, a0); a1 = dot2(w.x, h1, a1);
                h0 = __builtin_amdgcn_readlane(hu.x, i4 * 4 + 1);
                h1 = __builtin_amdgcn_readlane(hu.y, i4 * 4 + 1);
                a0 = dot2(w.y, h0, a0); a1 = dot2(w.y, h1, a1);
                h0 = __builtin_amdgcn_readlane(hu.x, i4 * 4 + 2);
                h1 = __builtin_amdgcn_readlane(hu.y, i4 * 4 + 2);
                a0 = dot2(w.z, h0, a0); a1 = dot2(w.z, h1, a1);
                h0 = __builtin_amdgcn_readlane(hu.x, i4 * 4 + 3);
                h1 = __builtin_amdgcn_readlane(hu.y, i4 * 4 + 3);
                a0 = dot2(w.w, h0, a0); a1 = dot2(w.w, h1, a1);
            }
            pA[kq][0][lane] = a0;
            pA[kq][1][lane] = a1;
        }
        __syncthreads();   // bar1: pA ready; both pollers of each word have read
        // re-arm polled words (one thread per word)
        if (t > 0 && kq != e && lane < 64) {
            unsigned long long* ap =
                reinterpret_cast<unsigned long long*>(
                    hbuf + ((size_t)((t & 1) * 64 + grp) * 4 + e) * 512)
                + (kq * 64 + l64);
            __hip_atomic_store(ap, ~0ull, __ATOMIC_RELAXED, __HIP_MEMORY_SCOPE_AGENT);
        }
        if (tid < 256) {
            float hs = xg0;
            if (t > 0) hs += pA[0][s][l] + pA[1][s][l] + pA[2][s][l] + pA[3][s][l];
            float hi = __shfl_down(hs, 1, 64);
            if ((l & 1) == 0) hsP[s][l >> 1] = pack2h(hs, hi);
        }
        __syncthreads();   // bar2: hsP ready
        // (5) phase B: readlane broadcast gate dots
        float b0a = 0.f, b1a = 0.f, b2a = 0.f, b3a = 0.f, b4a = 0.f;
        float b0b = 0.f, b1b = 0.f, b2b = 0.f, b3b = 0.f, b4b = 0.f;
        {
            unsigned hv = hsP[(l64 >> 4) & 1][kq * 16 + (l64 & 15)];
            #pragma unroll
            for (int i = 0; i < 16; ++i) {
                unsigned h0 = __builtin_amdgcn_readlane(hv, i);
                unsigned h1 = __builtin_amdgcn_readlane(hv, 16 + i);
                b0a = dot2(wg[0][i], h0, b0a); b0b = dot2(wg[0][i], h1, b0b);
                b1a = dot2(wg[1][i], h0, b1a); b1b = dot2(wg[1][i], h1, b1b);
                b2a = dot2(wg[2][i], h0, b2a); b2b = dot2(wg[2][i], h1, b2b);
                b3a = dot2(wg[3][i], h0, b3a); b3b = dot2(wg[3][i], h1, b3b);
                b4a = dot2(wg[4][i], h0, b4a); b4b = dot2(wg[4][i], h1, b4b);
            }
        }
        pB[kq][0][0][lane] = b0a; pB[kq][0][1][lane] = b1a; pB[kq][0][2][lane] = b2a;
        pB[kq][0][3][lane] = b3a; pB[kq][0][4][lane] = b4a;
        pB[kq][1][0][lane] = b0b; pB[kq][1][1][lane] = b1b; pB[kq][1][2][lane] = b2b;
        pB[kq][1][3][lane] = b3b; pB[kq][1][4][lane] = b4b;
        __syncthreads();   // bar3: pB ready
        // (6) cell update (tid<256); stash trap state in LDS
        if (tid < 256) {
            float ai = pB[0][s][0][l] + pB[1][s][0][l] + pB[2][s][0][l] + pB[3][s][0][l] + xgg0;
            float af = pB[0][s][1][l] + pB[1][s][1][l] + pB[2][s][1][l] + pB[3][s][1][l] + xgg1;
            float ad = pB[0][s][2][l] + pB[1][s][2][l] + pB[2][s][2][l] + pB[3][s][2][l] + xgg2;
            float ag = pB[0][s][3][l] + pB[1][s][3][l] + pB[2][s][3][l] + pB[3][s][3][l] + xgg3;
            float ao = pB[0][s][4][l] + pB[1][s][4][l] + pB[2][s][4][l] + pB[3][s][4][l] + xgg4;
            float ig = fast_sig(ai);
            float fg = fast_sig(af);
            float dl = __expf(ad);
            float gt = tanhf(ag);
            float og = fast_sig(ao);
            float gc = fmaf(fg, cst, ig * gt);
            float df = cst - gc;
            float dtv = dt_time[row0 + s];
            cst = fmaf(df, __expf(-dl * dtv), gc);
            float hn = og * tanhf(cst);
            float4 stv;
            stv.x = 2.f * gc; stv.y = 2.f * df; stv.z = dl * dtv; stv.w = av * og;
            cellSt[tid] = stv;
            float hi = __shfl_down(hn, 1, 64);
            if ((l & 1) == 0) hOut[s * 64 + (l >> 1)] = pack2h(hn, hi);
            float lm = av * hn;
            #pragma unroll
            for (int off = 32; off > 0; off >>= 1) lm += __shfl_down(lm, off, 64);
            if ((tid & 63) == 0) red[tid >> 6] = lm;
        }
        __syncthreads();   // bar4: hOut/red/cellSt ready; vmcnt drained
        if (tid == 0) {
            lam_out[(row0 + 0) * 4 + e] = red[0] + red[1];
            lam_out[(row0 + 1) * 4 + e] = red[2] + red[3];
        }
        // (7) publish FIRST: one 64-bit word per pair to each of 3 consumer copies
        if (tid < 192) {
            int cpy = tid >> 6;
            cpy += (cpy >= e) ? 1 : 0;
            int qp = tid & 63;
            unsigned long long v =
                ((unsigned long long)hOut[64 + qp] << 32) | (unsigned long long)hOut[qp];
            unsigned long long* dst =
                reinterpret_cast<unsigned long long*>(
                    hbuf + ((size_t)(((t + 1) & 1) * 64 + grp) * 4 + cpy) * 512)
                + (e * 64 + qp);
            __hip_atomic_store(dst, v, __ATOMIC_RELAXED, __HIP_MEMORY_SCOPE_AGENT);
        }
        // (8) trapezoid for THIS step, in the publish->poll latency window.
        //     tuple x = tid&255; tid<256 -> k=0..48, tid>=256 -> k=49..100.
        {
            const int x = tid & 255;
            float4 stv = cellSt[x];
            float g2 = stv.x, d2 = stv.y, q = stv.z, ao = stv.w;
            float r  = __expf(-0.01f * q);
            float r2 = r * r, r4 = r2 * r2;
            float T;
            if (tid < 256) {
                float E1 = r, E2 = r2, E3 = r2 * r, E4 = r4;
                float s1 = 0.f, s2 = 0.f, s3 = 0.f, s4 = 0.f;
                #pragma unroll
                for (int k = 0; k < 12; ++k) {      // k = 1..48
                    s1 += sig_e(fmaf(d2, E1, g2)); E1 *= r4;
                    s2 += sig_e(fmaf(d2, E2, g2)); E2 *= r4;
                    s3 += sig_e(fmaf(d2, E3, g2)); E3 *= r4;
                    s4 += sig_e(fmaf(d2, E4, g2)); E4 *= r4;
                }
                float sg0 = sig_e(g2 + d2);
                T = 48.5f - 2.f * ((s1 + s2) + (s3 + s4)) - sg0;
            } else {
                float E49 = __expf(-0.49f * q);
                float E1 = E49, E2 = E49 * r, E3 = E49 * r2, E4 = E49 * r2 * r;
                float s1 = 0.f, s2 = 0.f, s3 = 0.f, s4 = 0.f;
                #pragma unroll
                for (int k = 0; k < 13; ++k) {      // k = 49..100
                    s1 += sig_e(fmaf(d2, E1, g2)); E1 *= r4;
                    s2 += sig_e(fmaf(d2, E2, g2)); E2 *= r4;
                    s3 += sig_e(fmaf(d2, E3, g2)); E3 *= r4;
                    s4 += sig_e(fmaf(d2, E4, g2)); E4 *= r4;
                }
                float e100 = __expf(-q);
                float sg100 = sig_e(fmaf(d2, e100, g2));
                T = 51.5f - 2.f * ((s1 + s2) + (s3 + s4)) + sg100;
            }
            float v = ao * T;
            #pragma unroll
            for (int off = 32; off > 0; off >>= 1) v += __shfl_down(v, off, 64);
            if ((tid & 63) == 0) red2[tid >> 6] = v;
        }
        __syncthreads();   // bar5: red2 ready
        if (tid < 2) {
            float dtv = dt_time[row0 + tid];
            float v = (tid == 0) ? (red2[0] + red2[1] + red2[4] + red2[5])
                                 : (red2[2] + red2[3] + red2[6] + red2[7]);
            integ_out[(row0 + tid) * 4 + e] = v * (dtv * 0.01f);
        }
    }
}

extern "C" void kernel_launch(void* const* d_in, const int* in_sizes, int n_in,
                              void* d_out, int out_size, void* d_ws, size_t ws_size,
                              hipStream_t stream)
{
    const float* x_time  = (const float*)d_in[0];
    const float* dt_time = (const float*)d_in[1];
    const float* Wh_w = (const float*)d_in[2];
    const float* Wh_b = (const float*)d_in[3];
    const float* Wi_w = (const float*)d_in[4];
    const float* Wi_b = (const float*)d_in[5];
    const float* Wf_w = (const float*)d_in[6];
    const float* Wf_b = (const float*)d_in[7];
    const float* Wd_w = (const float*)d_in[8];
    const float* Wd_b = (const float*)d_in[9];
    const float* Wg_w = (const float*)d_in[10];
    const float* Wg_b = (const float*)d_in[11];
    const float* Wo_w = (const float*)d_in[12];
    const float* Wo_b = (const float*)d_in[13];
    const float* alpha = (const float*)d_in[14];

    float* ws = (float*)d_ws;
    float* XG   = ws + OFF_XG;
    unsigned* hbuf = (unsigned*)(ws + OFF_HBUF);
    float* lam_out   = (float*)d_out;
    float* integ_out = lam_out + 32 * 128 * 4;

    k0_pack<<<3072, 256, 0, stream>>>(Wh_w, Wh_b, Wi_w, Wi_b, Wf_w, Wf_b,
                                      Wd_w, Wd_b, Wg_w, Wg_b, Wo_w, Wo_b, ws);
    k1_xproj<<<3072, 256, 0, stream>>>(x_time, ws, XG);
    k2_recur<<<256, 512, 0, stream>>>(
        (const uint4*)(ws + OFF_WHHH), (const unsigned*)(ws + OFF_WGH),
        XG, dt_time, alpha, hbuf, lam_out, integ_out);
}